// Round 8
// baseline (729.595 us; speedup 1.0000x reference)
//
#include <hip/hip_runtime.h>
#include <cstdint>
#include <cstddef>

#define SCALE  0.08838834764831845f   // 128^-0.5
#define EPS_   1e-8f
#define LN_EPS_ 1e-5f

typedef unsigned short ushort_t;
typedef unsigned int uint_t;
typedef __attribute__((ext_vector_type(8))) short short8;
typedef __attribute__((ext_vector_type(4))) float f32x4;

// ---------------- workspace layout (float offsets), 19.2 MB ----------------
constexpr int OFF_GFD   = 0;        // 256   (f_w1@g_w)/DELTA  [h][2]
constexpr int OFF_CB    = 256;      // 128   f_w1@g_b + f_b1
constexpr int OFF_SP    = 448;      // 128
constexpr int OFF_SLOTS = 16960;    // 8192
constexpr int OFF_ZP    = 25152;    // 4096   [b][64][8]
constexpr int OFF_PP    = 29248;    // 8192   [b][64][8][2]
constexpr int OFF_UP    = 37440;    // 524288 [b][64][8][128]
constexpr int OFF_WKB   = 561728;   // bf16 [128][128] = 8192 float-slots
constexpr int OFF_WVB   = 569920;   // 8192
constexpr int OFF_FW2T  = 578112;   // f32 f_w2^T 16384
constexpr int OFF_BKT   = 594496;   // bf16 [b][128][4096] = 2097152 float-slots
constexpr int OFF_BV    = 2691648;  // bf16 [b][4096][128] = 2097152 float-slots
constexpr int OFF_CNT   = 4788800;  // 24 ints (3 iters x 8 b)
// end: 4788824 floats

__device__ __forceinline__ float waveReduceSum(float v) {
#pragma unroll
  for (int m = 1; m < 64; m <<= 1) v += __shfl_xor(v, m, 64);
  return v;
}
__device__ __forceinline__ float bf2f(uint_t u) { return __uint_as_float(u << 16); }
__device__ __forceinline__ ushort_t f2bf(float f) {
  uint_t u = __float_as_uint(f);
  return (ushort_t)((u + 0x7fffu + ((u >> 16) & 1u)) >> 16);
}

// batched 8-slot matvec: thread owns row d (half h of e-range); weights read
// once from global, activations broadcast from LDS. Returns full-row dot in
// acc[ s ] for BOTH h lanes (combined via shfl).
__device__ __forceinline__ void mv8(const float* __restrict__ W, int d, int h,
                                    const float (*src)[132], float* acc) {
  const float4* wr = (const float4*)(W + (size_t)d * 128 + h * 64);
#pragma unroll
  for (int s = 0; s < 8; ++s) acc[s] = 0.f;
#pragma unroll
  for (int e4 = 0; e4 < 16; ++e4) {
    float4 w4 = wr[e4];
#pragma unroll
    for (int s = 0; s < 8; ++s) {
      const float* sp_ = &src[s][h * 64 + e4 * 4];
      float a = acc[s];
      a = fmaf(w4.x, sp_[0], a);
      a = fmaf(w4.y, sp_[1], a);
      a = fmaf(w4.z, sp_[2], a);
      a = fmaf(w4.w, sp_[3], a);
      acc[s] = a;
    }
  }
#pragma unroll
  for (int s = 0; s < 8; ++s) acc[s] += __shfl_xor(acc[s], 1, 64);
}

// ---------------- fold weights + zero counters ----------------
__global__ __launch_bounds__(256) void kFold(
    const float* __restrict__ f_w1, const float* __restrict__ Wk,
    const float* __restrict__ Wv, const float* __restrict__ g_w,
    const float* __restrict__ g_b, const float* __restrict__ f_b1,
    const float* __restrict__ f_w2, float* __restrict__ ws) {
  int blk = blockIdx.x, tid = threadIdx.x;
  if (blk < 128) {
    int isV = blk >> 6;
    int idx = (blk & 63) * 256 + tid;           // 0..16383  (h*128+e)
    int h = idx >> 7, e = idx & 127;
    const float* Wm = isV ? Wv : Wk;
    float a = 0.f;
#pragma unroll 4
    for (int d = 0; d < 128; ++d) a = fmaf(f_w1[h * 128 + d], Wm[d * 128 + e], a);
    ((ushort_t*)(ws + (isV ? OFF_WVB : OFF_WKB)))[idx] = f2bf(a);
  } else if (blk == 128) {
    int h = tid >> 1, c = tid & 1;
    float a = 0.f;
    for (int d = 0; d < 128; ++d) a = fmaf(f_w1[h * 128 + d], g_w[d * 2 + c], a);
    ws[OFF_GFD + tid] = a * 0.2f;               // /DELTA (DELTA=5)
  } else if (blk == 129) {
    if (tid < 128) {
      float a = f_b1[tid];
      for (int d = 0; d < 128; ++d) a = fmaf(f_w1[tid * 128 + d], g_b[d], a);
      ws[OFF_CB + tid] = a;
    } else if (tid < 152) {
      ((int*)(ws + OFF_CNT))[tid - 128] = 0;
    }
  } else {
    for (int i = tid; i < 16384; i += 256)
      ws[OFF_FW2T + (i & 127) * 128 + (i >> 7)] = f_w2[i];
  }
}

// ---------------- MFMA base GEMMs (f32 inputs cast in-register) ----------------
__global__ __launch_bounds__(256) void kBase(const float* __restrict__ inputs,
                                             float* __restrict__ ws) {
  __shared__ __align__(16) char ep[17408];
  int tid = threadIdx.x, w = tid >> 6, l = tid & 63;
  int lr = l & 15, lg = l >> 4;
  int mat = blockIdx.y;
  int rowblk = blockIdx.x * 128;
  int b = blockIdx.x >> 5;
  int nb_in_b = (blockIdx.x & 31) * 128;
  const ushort_t* Wg = (const ushort_t*)(ws + (mat ? OFF_WVB : OFF_WKB));

  short8 afrag[2][4];
#pragma unroll
  for (int rt = 0; rt < 2; ++rt)
#pragma unroll
    for (int ks = 0; ks < 4; ++ks) {
      size_t row = (size_t)rowblk + w * 32 + rt * 16 + lr;
      const float* ip = inputs + row * 128 + ks * 32 + lg * 8;
      float4 x0 = *(const float4*)ip;
      float4 x1 = *(const float4*)(ip + 4);
      short8 fr;
      fr[0] = (short)f2bf(x0.x); fr[1] = (short)f2bf(x0.y);
      fr[2] = (short)f2bf(x0.z); fr[3] = (short)f2bf(x0.w);
      fr[4] = (short)f2bf(x1.x); fr[5] = (short)f2bf(x1.y);
      fr[6] = (short)f2bf(x1.z); fr[7] = (short)f2bf(x1.w);
      afrag[rt][ks] = fr;
    }
  float gf0a[8], gf1a[8], cba[8];
#pragma unroll
  for (int ct = 0; ct < 8; ++ct) {
    int c = ct * 16 + lr;
    gf0a[ct] = ws[OFF_GFD + c * 2 + 0];
    gf1a[ct] = ws[OFF_GFD + c * 2 + 1];
    cba[ct]  = ws[OFF_CB + c];
  }
  f32x4 acc[2][8];
#pragma unroll
  for (int rt = 0; rt < 2; ++rt)
#pragma unroll
    for (int ct = 0; ct < 8; ++ct) acc[rt][ct] = (f32x4){0.f, 0.f, 0.f, 0.f};
#pragma unroll 2
  for (int ct = 0; ct < 8; ++ct) {
    short8 bfr[4];
#pragma unroll
    for (int ks = 0; ks < 4; ++ks)
      bfr[ks] = *(const short8*)(Wg + (ct * 16 + lr) * 128 + ks * 32 + lg * 8);
#pragma unroll
    for (int ks = 0; ks < 4; ++ks) {
      acc[0][ct] = __builtin_amdgcn_mfma_f32_16x16x32_bf16(afrag[0][ks], bfr[ks], acc[0][ct], 0, 0, 0);
      acc[1][ct] = __builtin_amdgcn_mfma_f32_16x16x32_bf16(afrag[1][ks], bfr[ks], acc[1][ct], 0, 0, 0);
    }
  }
  ushort_t* outK = (ushort_t*)(ws + OFF_BKT);
  ushort_t* outV = (ushort_t*)(ws + OFF_BV);
  for (int h = 0; h < 2; ++h) {
    __syncthreads();
    if ((w >> 1) == h) {
      int nl0 = (w & 1) * 32 + lg * 4;
#pragma unroll
      for (int rt = 0; rt < 2; ++rt)
#pragma unroll
        for (int ct = 0; ct < 8; ++ct) {
          int c = ct * 16 + lr;
          ushort_t pk[4];
#pragma unroll
          for (int r = 0; r < 4; ++r) {
            int n = nb_in_b + h * 64 + nl0 + rt * 16 + r;
            float gy = -1.f + (float)(n >> 6) * (2.f / 63.f);
            float gx = -1.f + (float)(n & 63) * (2.f / 63.f);
            float o = acc[rt][ct][r] + gy * gf0a[ct] + gx * gf1a[ct] + cba[ct];
            pk[r] = f2bf(o);
          }
          if (mat == 0) {
            int byte = (c * 128 + (nl0 + rt * 16) * 2) ^ ((c & 7) << 4);
            *(uint2*)(ep + byte) = make_uint2(
                (uint_t)pk[0] | ((uint_t)pk[1] << 16),
                (uint_t)pk[2] | ((uint_t)pk[3] << 16));
          } else {
            int rb = nl0 + rt * 16;
#pragma unroll
            for (int r = 0; r < 4; ++r)
              *(ushort_t*)(ep + (rb + r) * 272 + c * 2) = pk[r];
          }
        }
    }
    __syncthreads();
    if (mat == 0) {
      for (int idx = tid; idx < 1024; idx += 256) {
        int c = idx >> 3, j = idx & 7;
        uint4 v = *(const uint4*)(ep + ((c * 128 + j * 16) ^ ((c & 7) << 4)));
        *(uint4*)(outK + ((size_t)(b * 128 + c)) * 4096 + nb_in_b + h * 64 + j * 8) = v;
      }
    } else {
      for (int idx = tid; idx < 1024; idx += 256) {
        int nl = idx >> 4, j = idx & 15;
        uint4 v = *(const uint4*)(ep + nl * 272 + j * 16);
        *(uint4*)(outV + ((size_t)rowblk + h * 64 + nl) * 128 + j * 8) = v;
      }
    }
  }
}

// ---------------- iteration kernel shared memory ----------------
struct SmIt {
  float2 OQl[8][128];     // 8 KB, persists across phases
  float qbl[8];
  int flag;
  union {
    struct { float yq[8][132]; float ql[8][132]; float qbp[4][8]; } qg;
    struct { float tp[64][37]; float al[64][13]; float Ush[4][8][132]; } at;
    struct { float zinv[8]; float ul[8][132]; float sl[8][132]; float xl[8][132];
             float yl[8][132]; float hml[8][132]; float redm[4][8]; float redv[4][8]; } cq;
  } u;
};

struct IterParams {
  const float *Wq, *f_w2, *f_b2;
  const float *wih, *whh, *bih, *bhh;
  const float *mw1, *mb1, *mw2, *mb2;
  const float *lnpg, *lnpb, *lnsg, *lnsb;
  float* ws;
};

// ---------------- one full slot-attention iteration ----------------
// grid 256 (= b*32 + chunkpair), block 256. Last-arriver block per b runs CQ8.
__global__ __launch_bounds__(256) void kIt(IterParams p, int it) {
  __shared__ SmIt S;
  float* ws = p.ws;
  int blk = blockIdx.x;
  int b = blk >> 5, cp = blk & 31;
  int tid = threadIdx.x, w = tid >> 6, lane = tid & 63;
  int sb = b * 8;

  // ======== phase A: redundant q-gen for this b's 8 slots ========
  {
    int s8 = tid >> 5, l32 = tid & 31;
    int bs = sb + s8;
    float4 x4 = *(const float4*)&ws[OFF_SLOTS + bs * 128 + l32 * 4];
    float s1 = x4.x + x4.y + x4.z + x4.w;
    float s2 = x4.x * x4.x + x4.y * x4.y + x4.z * x4.z + x4.w * x4.w;
#pragma unroll
    for (int m = 1; m < 32; m <<= 1) {
      s1 += __shfl_xor(s1, m, 32);
      s2 += __shfl_xor(s2, m, 32);
    }
    float mean = s1 * (1.f / 128.f);
    float var = s2 * (1.f / 128.f) - mean * mean;
    float rs = rsqrtf(var + LN_EPS_);
    float4 g4 = *(const float4*)&p.lnsg[l32 * 4];
    float4 b4 = *(const float4*)&p.lnsb[l32 * 4];
    float4 y4;
    y4.x = (x4.x - mean) * rs * g4.x + b4.x;
    y4.y = (x4.y - mean) * rs * g4.y + b4.y;
    y4.z = (x4.z - mean) * rs * g4.z + b4.z;
    y4.w = (x4.w - mean) * rs * g4.w + b4.w;
    *(float4*)&S.u.qg.yq[s8][l32 * 4] = y4;
  }
  __syncthreads();
  int d = tid >> 1, h = tid & 1;
  {
    float qa[8];
    mv8(p.Wq, d, h, S.u.qg.yq, qa);
    float fb = p.f_b2[d];
#pragma unroll
    for (int s = 0; s < 8; ++s) {
      float v = (h == 0) ? qa[s] * fb : 0.f;
      float r = waveReduceSum(v);
      if (lane == 0) S.u.qg.qbp[w][s] = r;
      if (h == 0) S.u.qg.ql[s][d] = qa[s];
    }
  }
  __syncthreads();
  {
    float qfa[8];
    mv8(ws + OFF_FW2T, d, h, S.u.qg.ql, qfa);
    if (tid < 8)
      S.qbl[tid] = (S.u.qg.qbp[0][tid] + S.u.qg.qbp[1][tid] +
                    S.u.qg.qbp[2][tid] + S.u.qg.qbp[3][tid]) * SCALE;
    if (h == 0) {
      float g0 = ws[OFF_GFD + d * 2 + 0], g1 = ws[OFF_GFD + d * 2 + 1];
#pragma unroll
      for (int s = 0; s < 8; ++s) {
        float sp0 = ws[OFF_SP + (sb + s) * 2 + 0];
        float sp1 = ws[OFF_SP + (sb + s) * 2 + 1];
        float offd = -(sp0 * g0 + sp1 * g1);
        S.OQl[s][d] = make_float2(offd, qfa[s] * SCALE);
      }
    }
  }
  __syncthreads();

  // ======== phase B: attention over 2 chunks ========
  float qbl[8];
#pragma unroll
  for (int s = 0; s < 8; ++s) qbl[s] = S.qbl[s];
  for (int half = 0; half < 2; ++half) {
    int chunk = cp * 2 + half;
    int n = chunk * 64 + lane;
    const ushort_t* kp = (const ushort_t*)(ws + OFF_BKT) +
                         (size_t)b * 524288 + (size_t)w * 32 * 4096 + n;
    float t[8];
#pragma unroll
    for (int s = 0; s < 8; ++s) t[s] = 0.f;
#pragma unroll 4
    for (int dd = 0; dd < 32; ++dd) {
      int dc = w * 32 + dd;
      float kv = bf2f((uint_t)kp[(size_t)dd * 4096]);
#pragma unroll
      for (int s = 0; s < 8; ++s) {
        float2 oq = S.OQl[s][dc];
        t[s] = fmaf(fmaxf(kv + oq.x, 0.f), oq.y, t[s]);
      }
    }
#pragma unroll
    for (int s = 0; s < 8; ++s) S.u.at.tp[lane][s * 4 + w] = t[s];
    __syncthreads();
    float a[8], den = 0.f;
#pragma unroll
    for (int s = 0; s < 8; ++s)
      t[s] = S.u.at.tp[lane][s * 4 + 0] + S.u.at.tp[lane][s * 4 + 1] +
             S.u.at.tp[lane][s * 4 + 2] + S.u.at.tp[lane][s * 4 + 3] + qbl[s];
    float mx = t[0];
#pragma unroll
    for (int s = 1; s < 8; ++s) mx = fmaxf(mx, t[s]);
#pragma unroll
    for (int s = 0; s < 8; ++s) { a[s] = __expf(t[s] - mx); den += a[s]; }
    float inv = 1.0f / den;
#pragma unroll
    for (int s = 0; s < 8; ++s) a[s] = fmaf(a[s], inv, EPS_);
    if (w == 0) {
      float gy = -1.f + (float)(n >> 6) * (2.f / 63.f);
      float gx = -1.f + (float)(n & 63) * (2.f / 63.f);
#pragma unroll
      for (int s = 0; s < 8; ++s) S.u.at.al[lane][s] = a[s];
#pragma unroll
      for (int s = 0; s < 8; ++s) {
        float z = waveReduceSum(a[s]);
        float p0 = waveReduceSum(a[s] * gy);
        float p1 = waveReduceSum(a[s] * gx);
        if (lane == 0) {
          ws[OFF_ZP + (b * 64 + chunk) * 8 + s] = z;
          ws[OFF_PP + ((b * 64 + chunk) * 8 + s) * 2 + 0] = p0;
          ws[OFF_PP + ((b * 64 + chunk) * 8 + s) * 2 + 1] = p1;
        }
      }
    }
    __syncthreads();

    int c0 = 2 * lane;
    float offv0[8], offv1[8];
#pragma unroll
    for (int s = 0; s < 8; ++s) {
      offv0[s] = S.OQl[s][c0].x;
      offv1[s] = S.OQl[s][c0 + 1].x;
    }
    float Ua0[8], Ua1[8];
#pragma unroll
    for (int s = 0; s < 8; ++s) { Ua0[s] = 0.f; Ua1[s] = 0.f; }
    const ushort_t* vp = (const ushort_t*)(ws + OFF_BV) +
                         ((size_t)(b * 4096 + chunk * 64 + w * 16)) * 128 + c0;
#pragma unroll 4
    for (int i = 0; i < 16; ++i) {
      uint_t vraw = *(const uint_t*)(vp + (size_t)i * 128);
      float v0 = bf2f(vraw & 0xffffu);
      float v1 = bf2f(vraw >> 16);
      int ii = w * 16 + i;
#pragma unroll
      for (int s = 0; s < 8; ++s) {
        float as = S.u.at.al[ii][s];
        Ua0[s] = fmaf(as, fmaxf(v0 + offv0[s], 0.f), Ua0[s]);
        Ua1[s] = fmaf(as, fmaxf(v1 + offv1[s], 0.f), Ua1[s]);
      }
    }
#pragma unroll
    for (int s = 0; s < 8; ++s)
      *(float2*)&S.u.at.Ush[w][s][c0] = make_float2(Ua0[s], Ua1[s]);
    __syncthreads();
    for (int f = tid; f < 1024; f += 256) {
      int s = f >> 7, c = f & 127;
      float v = S.u.at.Ush[0][s][c] + S.u.at.Ush[1][s][c] +
                S.u.at.Ush[2][s][c] + S.u.at.Ush[3][s][c];
      ws[OFF_UP + ((size_t)(b * 64 + chunk) * 8 + s) * 128 + c] = v;
    }
    __syncthreads();
  }

  // ======== phase C: last arriver per b finishes (GRU + MLP) ========
  __threadfence();                       // release: partials visible device-wide
  __syncthreads();
  if (tid == 0) {
    int old = atomicAdd((int*)(ws + OFF_CNT) + it * 8 + b, 1);
    S.flag = (old == 31) ? 1 : 0;
  }
  __syncthreads();
  if (!S.flag) return;
  __threadfence();                       // acquire side

  // Z / P reduction: s = tid>>5, l32 lanes over 64 chunks
  {
    int s8 = tid >> 5, l32 = tid & 31;
    float z = 0.f, q0 = 0.f, q1 = 0.f;
    for (int ch = l32; ch < 64; ch += 32) {
      z += ws[OFF_ZP + (b * 64 + ch) * 8 + s8];
      const float* pp = &ws[OFF_PP + ((size_t)((b * 64 + ch) * 8 + s8)) * 2];
      q0 += pp[0]; q1 += pp[1];
    }
#pragma unroll
    for (int m = 1; m < 32; m <<= 1) {
      z += __shfl_xor(z, m, 32);
      q0 += __shfl_xor(q0, m, 32);
      q1 += __shfl_xor(q1, m, 32);
    }
    if (l32 == 0) {
      float invZ = 1.f / z;
      S.u.cq.zinv[s8] = invZ;
      ws[OFF_SP + (sb + s8) * 2 + 0] = q0 * invZ;
      ws[OFF_SP + (sb + s8) * 2 + 1] = q1 * invZ;
    }
  }
  __syncthreads();
  // U sum + slots load
  {
    int s8 = tid >> 5, l32 = tid & 31;
    float4 u4 = {0.f, 0.f, 0.f, 0.f};
    const float* base = &ws[OFF_UP + ((size_t)(b * 64) * 8 + s8) * 128 + l32 * 4];
    for (int ch = 0; ch < 64; ++ch) {
      float4 t4 = *(const float4*)(base + (size_t)ch * 1024);
      u4.x += t4.x; u4.y += t4.y; u4.z += t4.z; u4.w += t4.w;
    }
    float iz = S.u.cq.zinv[s8];
    S.u.cq.ul[s8][l32 * 4 + 0] = u4.x * iz;
    S.u.cq.ul[s8][l32 * 4 + 1] = u4.y * iz;
    S.u.cq.ul[s8][l32 * 4 + 2] = u4.z * iz;
    S.u.cq.ul[s8][l32 * 4 + 3] = u4.w * iz;
    float4 s4 = *(const float4*)&ws[OFF_SLOTS + (sb + s8) * 128 + l32 * 4];
    *(float4*)&S.u.cq.sl[s8][l32 * 4] = s4;
  }
  __syncthreads();
  // updates through f_w2
  {
    float xa[8];
    mv8(p.f_w2, d, h, S.u.cq.ul, xa);
    float fb = p.f_b2[d];
    if (h == 0)
#pragma unroll
      for (int s = 0; s < 8; ++s) S.u.cq.xl[s][d] = xa[s] + fb;
  }
  __syncthreads();
  // GRU (6 batched matvecs, results in registers)
  float g_ir[8], g_iz[8], g_in[8], g_hr[8], g_hz[8], g_hn[8];
  mv8(p.wih,          d, h, S.u.cq.xl, g_ir);
  mv8(p.wih + 16384,  d, h, S.u.cq.xl, g_iz);
  mv8(p.wih + 32768,  d, h, S.u.cq.xl, g_in);
  mv8(p.whh,          d, h, S.u.cq.sl, g_hr);
  mv8(p.whh + 16384,  d, h, S.u.cq.sl, g_hz);
  mv8(p.whh + 32768,  d, h, S.u.cq.sl, g_hn);
  float hnew[8];
  {
    float b_ir = p.bih[d], b_iz = p.bih[128 + d], b_in = p.bih[256 + d];
    float b_hr = p.bhh[d], b_hz = p.bhh[128 + d], b_hn = p.bhh[256 + d];
#pragma unroll
    for (int s = 0; s < 8; ++s) {
      float rg = 1.f / (1.f + __expf(-(g_ir[s] + b_ir + g_hr[s] + b_hr)));
      float zg = 1.f / (1.f + __expf(-(g_iz[s] + b_iz + g_hz[s] + b_hz)));
      float ng = tanhf(g_in[s] + b_in + rg * (g_hn[s] + b_hn));
      hnew[s] = (1.f - zg) * ng + zg * S.u.cq.sl[s][d];
    }
  }
  // LN_pf reduce over d per slot
#pragma unroll
  for (int s = 0; s < 8; ++s) {
    float v1 = (h == 0) ? hnew[s] : 0.f;
    float v2 = (h == 0) ? hnew[s] * hnew[s] : 0.f;
    float r1 = waveReduceSum(v1);
    float r2 = waveReduceSum(v2);
    if (lane == 0) { S.u.cq.redm[w][s] = r1; S.u.cq.redv[w][s] = r2; }
  }
  __syncthreads();
  {
    float lg = p.lnpg[d], lb = p.lnpb[d];
#pragma unroll
    for (int s = 0; s < 8; ++s) {
      float mean = (S.u.cq.redm[0][s] + S.u.cq.redm[1][s] +
                    S.u.cq.redm[2][s] + S.u.cq.redm[3][s]) * (1.f / 128.f);
      float var = (S.u.cq.redv[0][s] + S.u.cq.redv[1][s] +
                   S.u.cq.redv[2][s] + S.u.cq.redv[3][s]) * (1.f / 128.f) - mean * mean;
      float y = (hnew[s] - mean) * rsqrtf(var + LN_EPS_) * lg + lb;
      if (h == 0) S.u.cq.yl[s][d] = y;
    }
  }
  __syncthreads();
  {
    float hm[8];
    mv8(p.mw1, d, h, S.u.cq.yl, hm);
    float mb = p.mb1[d];
    if (h == 0)
#pragma unroll
      for (int s = 0; s < 8; ++s) S.u.cq.hml[s][d] = fmaxf(hm[s] + mb, 0.f);
  }
  __syncthreads();
  {
    float oa[8];
    mv8(p.mw2, d, h, S.u.cq.hml, oa);
    float mb = p.mb2[d];
    if (h == 0)
#pragma unroll
      for (int s = 0; s < 8; ++s)
        ws[OFF_SLOTS + (sb + s) * 128 + d] = hnew[s] + mb + oa[s];
  }
}

// ---------------- write outputs ----------------
__global__ __launch_bounds__(256) void kOut(const float* __restrict__ ws,
                                            const float* __restrict__ S_r,
                                            const float* __restrict__ S_s,
                                            float* __restrict__ out) {
  int i = blockIdx.x * 256 + threadIdx.x;
  if (i < 8192) out[i] = ws[OFF_SLOTS + i];
  else if (i < 8320) out[i] = ws[OFF_SP + i - 8192];
  else if (i < 8576) out[i] = S_r[i - 8320];
  else if (i < 8704) out[i] = S_s[i - 8576];
}

extern "C" void kernel_launch(void* const* d_in, const int* in_sizes, int n_in,
                              void* d_out, int out_size, void* d_ws, size_t ws_size,
                              hipStream_t stream) {
  const float* inputs     = (const float*)d_in[0];
  const float* slots_init = (const float*)d_in[1];
  const float* S_p0       = (const float*)d_in[2];
  const float* S_s        = (const float*)d_in[3];
  const float* S_r        = (const float*)d_in[4];
  const float* Wq   = (const float*)d_in[5];
  const float* Wk   = (const float*)d_in[6];
  const float* Wv   = (const float*)d_in[7];
  const float* g_w  = (const float*)d_in[8];
  const float* g_b  = (const float*)d_in[9];
  const float* f_w1 = (const float*)d_in[10];
  const float* f_b1 = (const float*)d_in[11];
  const float* f_w2 = (const float*)d_in[12];
  const float* f_b2 = (const float*)d_in[13];
  const float* gwih = (const float*)d_in[14];
  const float* gwhh = (const float*)d_in[15];
  const float* gbih = (const float*)d_in[16];
  const float* gbhh = (const float*)d_in[17];
  const float* mw1  = (const float*)d_in[18];
  const float* mb1  = (const float*)d_in[19];
  const float* mw2  = (const float*)d_in[20];
  const float* mb2  = (const float*)d_in[21];
  const float* lnsg = (const float*)d_in[22];
  const float* lnsb = (const float*)d_in[23];
  const float* lnpg = (const float*)d_in[24];
  const float* lnpb = (const float*)d_in[25];
  float* ws  = (float*)d_ws;
  float* out = (float*)d_out;

  hipMemcpyAsync(ws + OFF_SLOTS, slots_init, 8192 * sizeof(float),
                 hipMemcpyDeviceToDevice, stream);
  hipMemcpyAsync(ws + OFF_SP, S_p0, 128 * sizeof(float),
                 hipMemcpyDeviceToDevice, stream);
  kFold<<<131, 256, 0, stream>>>(f_w1, Wk, Wv, g_w, g_b, f_b1, f_w2, ws);
  kBase<<<dim3(256, 2), 256, 0, stream>>>(inputs, ws);

  IterParams P;
  P.Wq = Wq; P.f_w2 = f_w2; P.f_b2 = f_b2;
  P.wih = gwih; P.whh = gwhh; P.bih = gbih; P.bhh = gbhh;
  P.mw1 = mw1; P.mb1 = mb1; P.mw2 = mw2; P.mb2 = mb2;
  P.lnpg = lnpg; P.lnpb = lnpb; P.lnsg = lnsg; P.lnsb = lnsb;
  P.ws = ws;
  for (int it = 0; it < 3; ++it)
    kIt<<<256, 256, 0, stream>>>(P, it);
  kOut<<<34, 256, 0, stream>>>(ws, S_r, S_s, out);
}

// Round 9
// 184.058 us; speedup vs baseline: 3.9639x; 3.9639x over previous
//
#include <hip/hip_runtime.h>
#include <cstdint>
#include <cstddef>

#define SCALE  0.08838834764831845f   // 128^-0.5
#define EPS_   1e-8f
#define LN_EPS_ 1e-5f

typedef unsigned short ushort_t;
typedef unsigned int uint_t;
typedef __attribute__((ext_vector_type(8))) short short8;
typedef __attribute__((ext_vector_type(4))) float f32x4;

// ---------------- workspace layout (float offsets), 19.2 MB ----------------
constexpr int OFF_GFD   = 0;        // 256   (f_w1@g_w)/DELTA  [h][2]
constexpr int OFF_CB    = 256;      // 128   f_w1@g_b + f_b1
constexpr int OFF_QB    = 384;      // 64
constexpr int OFF_SP    = 448;      // 128
constexpr int OFF_OQ    = 576;      // 16384 interleaved (off, qf*scale)
constexpr int OFF_SLOTS = 16960;    // 8192
constexpr int OFF_ZP    = 25152;    // 4096   [b][64][8]
constexpr int OFF_PP    = 29248;    // 8192   [b][64][8][2]
constexpr int OFF_UP    = 37440;    // 524288 [b][64][8][128]
constexpr int OFF_WKB   = 561728;   // bf16 [128][128] = 8192 float-slots
constexpr int OFF_WVB   = 569920;   // 8192
constexpr int OFF_FW2T  = 578112;   // f32 f_w2^T 16384
constexpr int OFF_BKT   = 594496;   // bf16 [b][128][4096] = 2097152 float-slots
constexpr int OFF_BV    = 2691648;  // bf16 [b][4096][128] = 2097152 float-slots
// end: 4788800 floats

__device__ __forceinline__ float waveReduceSum(float v) {
#pragma unroll
  for (int m = 1; m < 64; m <<= 1) v += __shfl_xor(v, m, 64);
  return v;
}
__device__ __forceinline__ float bf2f(uint_t u) { return __uint_as_float(u << 16); }
__device__ __forceinline__ ushort_t f2bf(float f) {
  uint_t u = __float_as_uint(f);
  return (ushort_t)((u + 0x7fffu + ((u >> 16) & 1u)) >> 16);
}

// half-row dot (e-range [h*64, h*64+64)), 16 independent float4 loads
__device__ __forceinline__ float halfDot(const float* __restrict__ Wrow,
                                         const float* xv, int h) {
  const float4* wr = (const float4*)Wrow + h * 16;
  const float4* xr = (const float4*)xv + h * 16;
  float4 a = {0.f, 0.f, 0.f, 0.f};
#pragma unroll
  for (int i = 0; i < 16; ++i) {
    float4 wv = wr[i], xq = xr[i];
    a.x = fmaf(wv.x, xq.x, a.x);
    a.y = fmaf(wv.y, xq.y, a.y);
    a.z = fmaf(wv.z, xq.z, a.z);
    a.w = fmaf(wv.w, xq.w, a.w);
  }
  return (a.x + a.y) + (a.z + a.w);
}

// quarter-row dot (e-range [h*32, h*32+32)), 8 independent float4 loads
__device__ __forceinline__ float quarterDot(const float* __restrict__ Wrow,
                                            const float* xv, int h) {
  const float4* wr = (const float4*)Wrow + h * 8;
  const float4* xr = (const float4*)xv + h * 8;
  float4 a = {0.f, 0.f, 0.f, 0.f};
#pragma unroll
  for (int i = 0; i < 8; ++i) {
    float4 wv = wr[i], xq = xr[i];
    a.x = fmaf(wv.x, xq.x, a.x);
    a.y = fmaf(wv.y, xq.y, a.y);
    a.z = fmaf(wv.z, xq.z, a.z);
    a.w = fmaf(wv.w, xq.w, a.w);
  }
  return (a.x + a.y) + (a.z + a.w);
}
__device__ __forceinline__ float quadSum(float v) {
  v += __shfl_xor(v, 1, 64);
  v += __shfl_xor(v, 2, 64);
  return v;
}

// ---------------- fold weights + init copies ----------------
__global__ __launch_bounds__(256) void kFold(
    const float* __restrict__ f_w1, const float* __restrict__ Wk,
    const float* __restrict__ Wv, const float* __restrict__ g_w,
    const float* __restrict__ g_b, const float* __restrict__ f_b1,
    const float* __restrict__ f_w2, const float* __restrict__ slots_init,
    const float* __restrict__ S_p0, float* __restrict__ ws) {
  int blk = blockIdx.x, tid = threadIdx.x;
  if (blk < 128) {
    int isV = blk >> 6;
    int idx = (blk & 63) * 256 + tid;           // 0..16383  (h*128+e)
    int h = idx >> 7, e = idx & 127;
    const float* Wm = isV ? Wv : Wk;
    float a = 0.f;
#pragma unroll 4
    for (int d = 0; d < 128; ++d) a = fmaf(f_w1[h * 128 + d], Wm[d * 128 + e], a);
    ((ushort_t*)(ws + (isV ? OFF_WVB : OFF_WKB)))[idx] = f2bf(a);
  } else if (blk == 128) {
    int h = tid >> 1, c = tid & 1;
    float a = 0.f;
    for (int d = 0; d < 128; ++d) a = fmaf(f_w1[h * 128 + d], g_w[d * 2 + c], a);
    ws[OFF_GFD + tid] = a * 0.2f;               // /DELTA (DELTA=5)
  } else if (blk == 129) {
    if (tid < 128) {
      float a = f_b1[tid];
      for (int d = 0; d < 128; ++d) a = fmaf(f_w1[tid * 128 + d], g_b[d], a);
      ws[OFF_CB + tid] = a;
    }
  } else if (blk == 130) {
    for (int i = tid; i < 16384; i += 256)
      ws[OFF_FW2T + (i & 127) * 128 + (i >> 7)] = f_w2[i];
  } else if (blk < 135) {
    int base = (blk - 131) * 2048 + tid * 8;    // slots copy, 8 floats/thread
    float4 a = *(const float4*)&slots_init[base];
    float4 b = *(const float4*)&slots_init[base + 4];
    *(float4*)&ws[OFF_SLOTS + base] = a;
    *(float4*)&ws[OFF_SLOTS + base + 4] = b;
  } else {
    if (tid < 128) ws[OFF_SP + tid] = S_p0[tid];
  }
}

// ---------------- MFMA base GEMMs (cast in-register) + initial q ----------------
struct QSm { float yl[128]; float ql[128]; float red[4]; float red2[4]; };

__device__ void doQ(int bs, const float* __restrict__ Wq,
                    const float* __restrict__ f_b2,
                    const float* __restrict__ lnsg,
                    const float* __restrict__ lnsb,
                    float* __restrict__ ws, QSm& S) {
  int t = threadIdx.x, w = t >> 6, lane = t & 63;
  int d = w * 32 + (lane >> 1), h = lane & 1;
  const float* FW2T = ws + OFF_FW2T;
  float x = ws[OFF_SLOTS + bs * 128 + d];
  float m1 = waveReduceSum(h == 0 ? x : 0.f);
  float m2 = waveReduceSum(h == 0 ? x * x : 0.f);
  if (lane == 0) { S.red[w] = m1; S.red2[w] = m2; }
  __syncthreads();
  float mean = (S.red[0] + S.red[1] + S.red[2] + S.red[3]) * (1.f / 128.f);
  float var = (S.red2[0] + S.red2[1] + S.red2[2] + S.red2[3]) * (1.f / 128.f) - mean * mean;
  if (h == 0) S.yl[d] = (x - mean) * rsqrtf(var + LN_EPS_) * lnsg[d] + lnsb[d];
  __syncthreads();
  float q = halfDot(Wq + (size_t)d * 128, S.yl, h);
  q += __shfl_xor(q, 1, 64);
  if (h == 0) S.ql[d] = q;
  __syncthreads();
  float qv = waveReduceSum(h == 0 ? q * f_b2[d] : 0.f);
  if (lane == 0) S.red[w] = qv;
  float qf = halfDot(FW2T + (size_t)d * 128, S.ql, h);
  qf += __shfl_xor(qf, 1, 64);
  __syncthreads();
  if (t == 0) ws[OFF_QB + bs] = (S.red[0] + S.red[1] + S.red[2] + S.red[3]) * SCALE;
  if (h == 0) {
    float sp0 = ws[OFF_SP + bs * 2 + 0], sp1 = ws[OFF_SP + bs * 2 + 1];
    float offd = -(sp0 * ws[OFF_GFD + d * 2 + 0] + sp1 * ws[OFF_GFD + d * 2 + 1]);
    ws[OFF_OQ + (bs * 128 + d) * 2 + 0] = offd;
    ws[OFF_OQ + (bs * 128 + d) * 2 + 1] = qf * SCALE;
  }
}

__global__ __launch_bounds__(256) void kBaseQ(const float* __restrict__ inputs,
                                              const float* __restrict__ Wq,
                                              const float* __restrict__ f_b2,
                                              const float* __restrict__ lnsg,
                                              const float* __restrict__ lnsb,
                                              float* __restrict__ ws) {
  __shared__ __align__(16) char smem[17408];
  int blk = blockIdx.x;
  if (blk >= 512) {       // initial q projection blocks
    doQ(blk - 512, Wq, f_b2, lnsg, lnsb, ws, *reinterpret_cast<QSm*>(smem));
    return;
  }
  char* ep = smem;
  int tid = threadIdx.x, w = tid >> 6, l = tid & 63;
  int lr = l & 15, lg = l >> 4;
  int mat = blk >> 8;
  int rb = blk & 255;
  int rowblk = rb * 128;
  int b = rb >> 5;
  int nb_in_b = (rb & 31) * 128;
  const ushort_t* Wg = (const ushort_t*)(ws + (mat ? OFF_WVB : OFF_WKB));

  short8 afrag[2][4];
#pragma unroll
  for (int rt = 0; rt < 2; ++rt)
#pragma unroll
    for (int ks = 0; ks < 4; ++ks) {
      size_t row = (size_t)rowblk + w * 32 + rt * 16 + lr;
      const float* ip = inputs + row * 128 + ks * 32 + lg * 8;
      float4 x0 = *(const float4*)ip;
      float4 x1 = *(const float4*)(ip + 4);
      short8 fr;
      fr[0] = (short)f2bf(x0.x); fr[1] = (short)f2bf(x0.y);
      fr[2] = (short)f2bf(x0.z); fr[3] = (short)f2bf(x0.w);
      fr[4] = (short)f2bf(x1.x); fr[5] = (short)f2bf(x1.y);
      fr[6] = (short)f2bf(x1.z); fr[7] = (short)f2bf(x1.w);
      afrag[rt][ks] = fr;
    }
  float gf0a[8], gf1a[8], cba[8];
#pragma unroll
  for (int ct = 0; ct < 8; ++ct) {
    int c = ct * 16 + lr;
    gf0a[ct] = ws[OFF_GFD + c * 2 + 0];
    gf1a[ct] = ws[OFF_GFD + c * 2 + 1];
    cba[ct]  = ws[OFF_CB + c];
  }
  f32x4 acc[2][8];
#pragma unroll
  for (int rt = 0; rt < 2; ++rt)
#pragma unroll
    for (int ct = 0; ct < 8; ++ct) acc[rt][ct] = (f32x4){0.f, 0.f, 0.f, 0.f};
#pragma unroll 2
  for (int ct = 0; ct < 8; ++ct) {
    short8 bfr[4];
#pragma unroll
    for (int ks = 0; ks < 4; ++ks)
      bfr[ks] = *(const short8*)(Wg + (ct * 16 + lr) * 128 + ks * 32 + lg * 8);
#pragma unroll
    for (int ks = 0; ks < 4; ++ks) {
      acc[0][ct] = __builtin_amdgcn_mfma_f32_16x16x32_bf16(afrag[0][ks], bfr[ks], acc[0][ct], 0, 0, 0);
      acc[1][ct] = __builtin_amdgcn_mfma_f32_16x16x32_bf16(afrag[1][ks], bfr[ks], acc[1][ct], 0, 0, 0);
    }
  }
  ushort_t* outK = (ushort_t*)(ws + OFF_BKT);
  ushort_t* outV = (ushort_t*)(ws + OFF_BV);
  for (int h = 0; h < 2; ++h) {
    __syncthreads();
    if ((w >> 1) == h) {
      int nl0 = (w & 1) * 32 + lg * 4;
#pragma unroll
      for (int rt = 0; rt < 2; ++rt)
#pragma unroll
        for (int ct = 0; ct < 8; ++ct) {
          int c = ct * 16 + lr;
          ushort_t pk[4];
#pragma unroll
          for (int r = 0; r < 4; ++r) {
            int n = nb_in_b + h * 64 + nl0 + rt * 16 + r;
            float gy = -1.f + (float)(n >> 6) * (2.f / 63.f);
            float gx = -1.f + (float)(n & 63) * (2.f / 63.f);
            float o = acc[rt][ct][r] + gy * gf0a[ct] + gx * gf1a[ct] + cba[ct];
            pk[r] = f2bf(o);
          }
          if (mat == 0) {
            int byte = (c * 128 + (nl0 + rt * 16) * 2) ^ ((c & 7) << 4);
            *(uint2*)(ep + byte) = make_uint2(
                (uint_t)pk[0] | ((uint_t)pk[1] << 16),
                (uint_t)pk[2] | ((uint_t)pk[3] << 16));
          } else {
            int rbw = nl0 + rt * 16;
#pragma unroll
            for (int r = 0; r < 4; ++r)
              *(ushort_t*)(ep + (rbw + r) * 272 + c * 2) = pk[r];
          }
        }
    }
    __syncthreads();
    if (mat == 0) {
      for (int idx = tid; idx < 1024; idx += 256) {
        int c = idx >> 3, j = idx & 7;
        uint4 v = *(const uint4*)(ep + ((c * 128 + j * 16) ^ ((c & 7) << 4)));
        *(uint4*)(outK + ((size_t)(b * 128 + c)) * 4096 + nb_in_b + h * 64 + j * 8) = v;
      }
    } else {
      for (int idx = tid; idx < 1024; idx += 256) {
        int nl = idx >> 4, j = idx & 15;
        uint4 v = *(const uint4*)(ep + nl * 272 + j * 16);
        *(uint4*)(outV + ((size_t)rowblk + h * 64 + nl) * 128 + j * 8) = v;
      }
    }
  }
}

// ---------------- fused attention: 4 waves, d-split / i-split ----------------
__global__ __launch_bounds__(256) void kAttn(float* __restrict__ ws) {
  __shared__ float OFFl[8][128];     // split (was float2 OQl -> 8-way conflict)
  __shared__ float QFl[8][128];
  __shared__ float tp[64][37];
  __shared__ float al[64][13];
  __shared__ float Ush[4][8][132];
  int b = blockIdx.x >> 6, chunk = blockIdx.x & 63;
  int tid = threadIdx.x, w = tid >> 6, lane = tid & 63;
  int sb = b * 8;
  for (int f = tid; f < 1024; f += 256) {
    int s = f >> 7, d = f & 127;
    float2 oq = *(const float2*)&ws[OFF_OQ + ((sb + s) * 128 + d) * 2];
    OFFl[s][d] = oq.x;
    QFl[s][d] = oq.y;
  }
  float qbl[8];
#pragma unroll
  for (int s = 0; s < 8; ++s) qbl[s] = ws[OFF_QB + sb + s];
  __syncthreads();

  int n = chunk * 64 + lane;
  const ushort_t* kp = (const ushort_t*)(ws + OFF_BKT) +
                       (size_t)b * 524288 + (size_t)w * 32 * 4096 + n;
  float t[8];
#pragma unroll
  for (int s = 0; s < 8; ++s) t[s] = 0.f;
#pragma unroll 4
  for (int dd = 0; dd < 32; ++dd) {
    int d = w * 32 + dd;
    float kv = bf2f((uint_t)kp[(size_t)dd * 4096]);
#pragma unroll
    for (int s = 0; s < 8; ++s)
      t[s] = fmaf(fmaxf(kv + OFFl[s][d], 0.f), QFl[s][d], t[s]);
  }
#pragma unroll
  for (int s = 0; s < 8; ++s) tp[lane][s * 4 + w] = t[s];
  __syncthreads();
  float a[8], den = 0.f;
#pragma unroll
  for (int s = 0; s < 8; ++s)
    t[s] = tp[lane][s * 4 + 0] + tp[lane][s * 4 + 1] +
           tp[lane][s * 4 + 2] + tp[lane][s * 4 + 3] + qbl[s];
  float mx = t[0];
#pragma unroll
  for (int s = 1; s < 8; ++s) mx = fmaxf(mx, t[s]);
#pragma unroll
  for (int s = 0; s < 8; ++s) { a[s] = __expf(t[s] - mx); den += a[s]; }
  float inv = 1.0f / den;
#pragma unroll
  for (int s = 0; s < 8; ++s) a[s] = fmaf(a[s], inv, EPS_);
  if (w == 0) {
    float gy = -1.f + (float)(n >> 6) * (2.f / 63.f);
    float gx = -1.f + (float)(n & 63) * (2.f / 63.f);
#pragma unroll
    for (int s = 0; s < 8; ++s) al[lane][s] = a[s];
#pragma unroll
    for (int s = 0; s < 8; ++s) {
      float z = waveReduceSum(a[s]);
      float p0 = waveReduceSum(a[s] * gy);
      float p1 = waveReduceSum(a[s] * gx);
      if (lane == 0) {
        ws[OFF_ZP + (b * 64 + chunk) * 8 + s] = z;
        ws[OFF_PP + ((b * 64 + chunk) * 8 + s) * 2 + 0] = p0;
        ws[OFF_PP + ((b * 64 + chunk) * 8 + s) * 2 + 1] = p1;
      }
    }
  }
  __syncthreads();

  int c0 = 2 * lane;
  float offv0[8], offv1[8];
#pragma unroll
  for (int s = 0; s < 8; ++s) {
    offv0[s] = OFFl[s][c0];          // stride-2 float: 2-way conflict (free)
    offv1[s] = OFFl[s][c0 + 1];
  }
  float Ua0[8], Ua1[8];
#pragma unroll
  for (int s = 0; s < 8; ++s) { Ua0[s] = 0.f; Ua1[s] = 0.f; }
  const ushort_t* vp = (const ushort_t*)(ws + OFF_BV) +
                       ((size_t)(b * 4096 + chunk * 64 + w * 16)) * 128 + c0;
#pragma unroll 4
  for (int i = 0; i < 16; ++i) {
    uint_t vraw = *(const uint_t*)(vp + (size_t)i * 128);
    float v0 = bf2f(vraw & 0xffffu);
    float v1 = bf2f(vraw >> 16);
    int ii = w * 16 + i;
#pragma unroll
    for (int s = 0; s < 8; ++s) {
      float as = al[ii][s];
      Ua0[s] = fmaf(as, fmaxf(v0 + offv0[s], 0.f), Ua0[s]);
      Ua1[s] = fmaf(as, fmaxf(v1 + offv1[s], 0.f), Ua1[s]);
    }
  }
#pragma unroll
  for (int s = 0; s < 8; ++s) {
    Ush[w][s][c0] = Ua0[s];          // two float stores: 2-way (free)
    Ush[w][s][c0 + 1] = Ua1[s];
  }
  __syncthreads();
  for (int f = tid; f < 1024; f += 256) {
    int s = f >> 7, c = f & 127;
    float v = Ush[0][s][c] + Ush[1][s][c] + Ush[2][s][c] + Ush[3][s][c];
    ws[OFF_UP + ((size_t)(b * 64 + chunk) * 8 + s) * 128 + c] = v;
  }
}

// ---------------- fused: finalize + GRU + post-MLP + next-iter q ----------------
// 512 thr: d = t>>2 (0..127), h = t&3 (e-quarter). last: also writes d_out.
__global__ __launch_bounds__(512) void kCQ(
    const float* __restrict__ Wq, const float* __restrict__ f_w2,
    const float* __restrict__ f_b2, const float* __restrict__ wih,
    const float* __restrict__ whh, const float* __restrict__ bih,
    const float* __restrict__ bhh, const float* __restrict__ mw1,
    const float* __restrict__ mb1, const float* __restrict__ mw2,
    const float* __restrict__ mb2, const float* __restrict__ lnpg,
    const float* __restrict__ lnpb, const float* __restrict__ lnsg,
    const float* __restrict__ lnsb, const float* __restrict__ S_r,
    const float* __restrict__ S_s, float* __restrict__ ws,
    float* __restrict__ out, int last) {
  int bs = blockIdx.x;
  int t = threadIdx.x;
  if (bs == 64) {         // only on last iter: S_r / S_s passthrough
    if (t < 256) out[8320 + t] = S_r[t];
    else if (t < 384) out[8576 + t - 256] = S_s[t - 256];
    return;
  }
  int b = bs >> 3, s = bs & 7;
  int w = t >> 6, lane = t & 63;
  int d = t >> 2, h = t & 3;
  __shared__ __align__(16) float ul[128], xl[128], sl[128], yl[128], hml[128];
  __shared__ float red[8], red2[8];
  const float* FW2T = ws + OFF_FW2T;
  float zv = ws[OFF_ZP + (b * 64 + lane) * 8 + s];
  float2 pv = *(const float2*)&ws[OFF_PP + ((size_t)(b * 64 + lane) * 8 + s) * 2];
  float Z = waveReduceSum(zv);
  float P0 = waveReduceSum(pv.x);
  float P1 = waveReduceSum(pv.y);
  float invZ = 1.f / Z, sp0 = P0 * invZ, sp1 = P1 * invZ;
  float u = 0.f;
  const float* up = ws + OFF_UP + ((size_t)(b * 64 + h * 16) * 8 + s) * 128 + d;
#pragma unroll
  for (int ch = 0; ch < 16; ++ch) u += up[(size_t)ch * 1024];
  u = quadSum(u);
  if (h == 0) { ul[d] = u * invZ; sl[d] = ws[OFF_SLOTS + bs * 128 + d]; }
  if (t == 0) {
    ws[OFF_SP + bs * 2 + 0] = sp0;
    ws[OFF_SP + bs * 2 + 1] = sp1;
    if (last) {
      out[8192 + bs * 2 + 0] = sp0;
      out[8192 + bs * 2 + 1] = sp1;
    }
  }
  __syncthreads();
  float xa = quadSum(quarterDot(f_w2 + (size_t)d * 128, ul, h));
  if (h == 0) xl[d] = xa + f_b2[d];
  __syncthreads();
  float ir = quarterDot(wih + (size_t)d * 128, xl, h);
  float iz = quarterDot(wih + (size_t)(128 + d) * 128, xl, h);
  float in_ = quarterDot(wih + (size_t)(256 + d) * 128, xl, h);
  float hr = quarterDot(whh + (size_t)d * 128, sl, h);
  float hz = quarterDot(whh + (size_t)(128 + d) * 128, sl, h);
  float hn = quarterDot(whh + (size_t)(256 + d) * 128, sl, h);
  ir = quadSum(ir); iz = quadSum(iz); in_ = quadSum(in_);
  hr = quadSum(hr); hz = quadSum(hz); hn = quadSum(hn);
  float hnew = 0.f;
  if (h == 0) {
    float rg = 1.f / (1.f + __expf(-(ir + bih[d] + hr + bhh[d])));
    float zg = 1.f / (1.f + __expf(-(iz + bih[128 + d] + hz + bhh[128 + d])));
    float ng = tanhf(in_ + bih[256 + d] + rg * (hn + bhh[256 + d]));
    hnew = (1.f - zg) * ng + zg * sl[d];
  }
  float m1 = waveReduceSum(h == 0 ? hnew : 0.f);
  float m2 = waveReduceSum(h == 0 ? hnew * hnew : 0.f);
  if (lane == 0) { red[w] = m1; red2[w] = m2; }
  __syncthreads();
  float mean = 0.f, var = 0.f;
#pragma unroll
  for (int i = 0; i < 8; ++i) { mean += red[i]; var += red2[i]; }
  mean *= (1.f / 128.f);
  var = var * (1.f / 128.f) - mean * mean;
  if (h == 0) yl[d] = (hnew - mean) * rsqrtf(var + LN_EPS_) * lnpg[d] + lnpb[d];
  __syncthreads();
  float hm = quadSum(quarterDot(mw1 + (size_t)d * 128, yl, h));
  if (h == 0) hml[d] = fmaxf(hm + mb1[d], 0.f);
  __syncthreads();
  float oa = quadSum(quarterDot(mw2 + (size_t)d * 128, hml, h));
  float o = 0.f;
  if (h == 0) {
    o = hnew + mb2[d] + oa;
    ws[OFF_SLOTS + bs * 128 + d] = o;
    if (last) out[bs * 128 + d] = o;
  }
  float n1 = waveReduceSum(h == 0 ? o : 0.f);
  float n2 = waveReduceSum(h == 0 ? o * o : 0.f);
  if (lane == 0) { red[w] = n1; red2[w] = n2; }
  __syncthreads();
  float mean2 = 0.f, var2 = 0.f;
#pragma unroll
  for (int i = 0; i < 8; ++i) { mean2 += red[i]; var2 += red2[i]; }
  mean2 *= (1.f / 128.f);
  var2 = var2 * (1.f / 128.f) - mean2 * mean2;
  if (h == 0) yl[d] = (o - mean2) * rsqrtf(var2 + LN_EPS_) * lnsg[d] + lnsb[d];
  __syncthreads();
  float q = quadSum(quarterDot(Wq + (size_t)d * 128, yl, h));
  if (h == 0) xl[d] = q;
  __syncthreads();
  float qv = waveReduceSum(h == 0 ? q * f_b2[d] : 0.f);
  if (lane == 0) red[w] = qv;
  float qf = quadSum(quarterDot(FW2T + (size_t)d * 128, xl, h));
  __syncthreads();
  if (t == 0) {
    float qb = 0.f;
#pragma unroll
    for (int i = 0; i < 8; ++i) qb += red[i];
    ws[OFF_QB + bs] = qb * SCALE;
  }
  if (h == 0) {
    float offd = -(sp0 * ws[OFF_GFD + d * 2 + 0] + sp1 * ws[OFF_GFD + d * 2 + 1]);
    ws[OFF_OQ + (bs * 128 + d) * 2 + 0] = offd;
    ws[OFF_OQ + (bs * 128 + d) * 2 + 1] = qf * SCALE;
  }
}

extern "C" void kernel_launch(void* const* d_in, const int* in_sizes, int n_in,
                              void* d_out, int out_size, void* d_ws, size_t ws_size,
                              hipStream_t stream) {
  const float* inputs     = (const float*)d_in[0];
  const float* slots_init = (const float*)d_in[1];
  const float* S_p0       = (const float*)d_in[2];
  const float* S_s        = (const float*)d_in[3];
  const float* S_r        = (const float*)d_in[4];
  const float* Wq   = (const float*)d_in[5];
  const float* Wk   = (const float*)d_in[6];
  const float* Wv   = (const float*)d_in[7];
  const float* g_w  = (const float*)d_in[8];
  const float* g_b  = (const float*)d_in[9];
  const float* f_w1 = (const float*)d_in[10];
  const float* f_b1 = (const float*)d_in[11];
  const float* f_w2 = (const float*)d_in[12];
  const float* f_b2 = (const float*)d_in[13];
  const float* gwih = (const float*)d_in[14];
  const float* gwhh = (const float*)d_in[15];
  const float* gbih = (const float*)d_in[16];
  const float* gbhh = (const float*)d_in[17];
  const float* mw1  = (const float*)d_in[18];
  const float* mb1  = (const float*)d_in[19];
  const float* mw2  = (const float*)d_in[20];
  const float* mb2  = (const float*)d_in[21];
  const float* lnsg = (const float*)d_in[22];
  const float* lnsb = (const float*)d_in[23];
  const float* lnpg = (const float*)d_in[24];
  const float* lnpb = (const float*)d_in[25];
  float* ws  = (float*)d_ws;
  float* out = (float*)d_out;

  kFold<<<136, 256, 0, stream>>>(f_w1, Wk, Wv, g_w, g_b, f_b1, f_w2,
                                 slots_init, S_p0, ws);
  kBaseQ<<<576, 256, 0, stream>>>(inputs, Wq, f_b2, lnsg, lnsb, ws);
  for (int it = 0; it < 3; ++it) {
    int last = (it == 2);
    kAttn<<<512, 256, 0, stream>>>(ws);
    kCQ<<<64 + last, 512, 0, stream>>>(Wq, f_w2, f_b2, gwih, gwhh, gbih, gbhh,
                                       mw1, mb1, mw2, mb2, lnpg, lnpb,
                                       lnsg, lnsb, S_r, S_s, ws, out, last);
  }
}

// Round 10
// 177.394 us; speedup vs baseline: 4.1129x; 1.0376x over previous
//
#include <hip/hip_runtime.h>
#include <cstdint>
#include <cstddef>

#define SCALE  0.08838834764831845f   // 128^-0.5
#define EPS_   1e-8f
#define LN_EPS_ 1e-5f

typedef unsigned short ushort_t;
typedef unsigned int uint_t;
typedef __attribute__((ext_vector_type(8))) short short8;
typedef __attribute__((ext_vector_type(4))) float f32x4;

// ---------------- workspace layout (float offsets), 23.3 MB ----------------
constexpr int OFF_GFD   = 0;        // 256   (f_w1@g_w)/DELTA  [h][2]
constexpr int OFF_CB    = 256;      // 128   f_w1@g_b + f_b1
constexpr int OFF_QB    = 384;      // 64
constexpr int OFF_SP    = 448;      // 128
constexpr int OFF_OQ    = 576;      // 16384 interleaved (off, qf*scale)
constexpr int OFF_SLOTS = 16960;    // 8192
constexpr int OFF_ZP    = 25152;    // 4096   [b][64][8]
constexpr int OFF_PP    = 29248;    // 8192   [b][64][8][2]
constexpr int OFF_UP    = 37440;    // 524288 [b][64][8][128]
constexpr int OFF_WKB   = 561728;   // bf16 [128][128] = 8192 float-slots
constexpr int OFF_WVB   = 569920;   // 8192
constexpr int OFF_FW2T  = 578112;   // f32 f_w2^T 16384
constexpr int OFF_BKT   = 594496;   // uint [b][64 dp][4096 n] = 2097152 float-slots
constexpr int OFF_BV    = 2691648;  // bf16 [b][4096][128] = 2097152 float-slots
constexpr int OFF_AB    = 4788800;  // bf16 inputs [32768][128] = 1048576*2... 2097152 bf16 = 1048576 slots
// end: 5837376 floats

__device__ __forceinline__ float waveReduceSum(float v) {
#pragma unroll
  for (int m = 1; m < 64; m <<= 1) v += __shfl_xor(v, m, 64);
  return v;
}
__device__ __forceinline__ float bf2f(uint_t u) { return __uint_as_float(u << 16); }
__device__ __forceinline__ ushort_t f2bf(float f) {
  uint_t u = __float_as_uint(f);
  return (ushort_t)((u + 0x7fffu + ((u >> 16) & 1u)) >> 16);
}

// half-row dot (e-range [h*64, h*64+64)), 16 independent float4 loads
__device__ __forceinline__ float halfDot(const float* __restrict__ Wrow,
                                         const float* xv, int h) {
  const float4* wr = (const float4*)Wrow + h * 16;
  const float4* xr = (const float4*)xv + h * 16;
  float4 a = {0.f, 0.f, 0.f, 0.f};
#pragma unroll
  for (int i = 0; i < 16; ++i) {
    float4 wv = wr[i], xq = xr[i];
    a.x = fmaf(wv.x, xq.x, a.x);
    a.y = fmaf(wv.y, xq.y, a.y);
    a.z = fmaf(wv.z, xq.z, a.z);
    a.w = fmaf(wv.w, xq.w, a.w);
  }
  return (a.x + a.y) + (a.z + a.w);
}

// quarter-row dot (e-range [h*32, h*32+32)), 8 independent float4 loads
__device__ __forceinline__ float quarterDot(const float* __restrict__ Wrow,
                                            const float* xv, int h) {
  const float4* wr = (const float4*)Wrow + h * 8;
  const float4* xr = (const float4*)xv + h * 8;
  float4 a = {0.f, 0.f, 0.f, 0.f};
#pragma unroll
  for (int i = 0; i < 8; ++i) {
    float4 wv = wr[i], xq = xr[i];
    a.x = fmaf(wv.x, xq.x, a.x);
    a.y = fmaf(wv.y, xq.y, a.y);
    a.z = fmaf(wv.z, xq.z, a.z);
    a.w = fmaf(wv.w, xq.w, a.w);
  }
  return (a.x + a.y) + (a.z + a.w);
}
__device__ __forceinline__ float quadSum(float v) {
  v += __shfl_xor(v, 1, 64);
  v += __shfl_xor(v, 2, 64);
  return v;
}

// ---------------- fold weights + init copies + input cast ----------------
__global__ __launch_bounds__(256) void kFold(
    const float* __restrict__ f_w1, const float* __restrict__ Wk,
    const float* __restrict__ Wv, const float* __restrict__ g_w,
    const float* __restrict__ g_b, const float* __restrict__ f_b1,
    const float* __restrict__ f_w2, const float* __restrict__ slots_init,
    const float* __restrict__ S_p0, const float* __restrict__ inputs,
    float* __restrict__ ws) {
  int blk = blockIdx.x, tid = threadIdx.x;
  if (blk < 128) {
    int isV = blk >> 6;
    int idx = (blk & 63) * 256 + tid;           // 0..16383  (h*128+e)
    int h = idx >> 7, e = idx & 127;
    const float* Wm = isV ? Wv : Wk;
    float a = 0.f;
#pragma unroll 4
    for (int d = 0; d < 128; ++d) a = fmaf(f_w1[h * 128 + d], Wm[d * 128 + e], a);
    ((ushort_t*)(ws + (isV ? OFF_WVB : OFF_WKB)))[idx] = f2bf(a);
  } else if (blk == 128) {
    int h = tid >> 1, c = tid & 1;
    float a = 0.f;
    for (int d = 0; d < 128; ++d) a = fmaf(f_w1[h * 128 + d], g_w[d * 2 + c], a);
    ws[OFF_GFD + tid] = a * 0.2f;               // /DELTA (DELTA=5)
  } else if (blk == 129) {
    if (tid < 128) {
      float a = f_b1[tid];
      for (int d = 0; d < 128; ++d) a = fmaf(f_w1[tid * 128 + d], g_b[d], a);
      ws[OFF_CB + tid] = a;
    }
  } else if (blk == 130) {
    for (int i = tid; i < 16384; i += 256)
      ws[OFF_FW2T + (i & 127) * 128 + (i >> 7)] = f_w2[i];
  } else if (blk < 135) {
    int base = (blk - 131) * 2048 + tid * 8;    // slots copy, 8 floats/thread
    float4 a = *(const float4*)&slots_init[base];
    float4 b = *(const float4*)&slots_init[base + 4];
    *(float4*)&ws[OFF_SLOTS + base] = a;
    *(float4*)&ws[OFF_SLOTS + base + 4] = b;
  } else if (blk == 135) {
    if (tid < 128) ws[OFF_SP + tid] = S_p0[tid];
  } else {
    // input cast: blocks 136..391, 8 floats per thread
    int idx = (blk - 136) * 256 + tid;          // 0..65535
    const float4* src = (const float4*)(inputs + (size_t)idx * 8);
    float4 a = src[0], b = src[1];
    uint_t p0 = (uint_t)f2bf(a.x) | ((uint_t)f2bf(a.y) << 16);
    uint_t p1 = (uint_t)f2bf(a.z) | ((uint_t)f2bf(a.w) << 16);
    uint_t p2 = (uint_t)f2bf(b.x) | ((uint_t)f2bf(b.y) << 16);
    uint_t p3 = (uint_t)f2bf(b.z) | ((uint_t)f2bf(b.w) << 16);
    ((uint4*)((ushort_t*)(ws + OFF_AB)))[idx] = make_uint4(p0, p1, p2, p3);
  }
}

// ---------------- MFMA base GEMMs + initial q ----------------
struct QSm { float yl[128]; float ql[128]; float red[4]; float red2[4]; };

__device__ void doQ(int bs, const float* __restrict__ Wq,
                    const float* __restrict__ f_b2,
                    const float* __restrict__ lnsg,
                    const float* __restrict__ lnsb,
                    float* __restrict__ ws, QSm& S) {
  int t = threadIdx.x, w = t >> 6, lane = t & 63;
  int d = w * 32 + (lane >> 1), h = lane & 1;
  const float* FW2T = ws + OFF_FW2T;
  float x = ws[OFF_SLOTS + bs * 128 + d];
  float m1 = waveReduceSum(h == 0 ? x : 0.f);
  float m2 = waveReduceSum(h == 0 ? x * x : 0.f);
  if (lane == 0) { S.red[w] = m1; S.red2[w] = m2; }
  __syncthreads();
  float mean = (S.red[0] + S.red[1] + S.red[2] + S.red[3]) * (1.f / 128.f);
  float var = (S.red2[0] + S.red2[1] + S.red2[2] + S.red2[3]) * (1.f / 128.f) - mean * mean;
  if (h == 0) S.yl[d] = (x - mean) * rsqrtf(var + LN_EPS_) * lnsg[d] + lnsb[d];
  __syncthreads();
  float q = halfDot(Wq + (size_t)d * 128, S.yl, h);
  q += __shfl_xor(q, 1, 64);
  if (h == 0) S.ql[d] = q;
  __syncthreads();
  float qv = waveReduceSum(h == 0 ? q * f_b2[d] : 0.f);
  if (lane == 0) S.red[w] = qv;
  float qf = halfDot(FW2T + (size_t)d * 128, S.ql, h);
  qf += __shfl_xor(qf, 1, 64);
  __syncthreads();
  if (t == 0) ws[OFF_QB + bs] = (S.red[0] + S.red[1] + S.red[2] + S.red[3]) * SCALE;
  if (h == 0) {
    float sp0 = ws[OFF_SP + bs * 2 + 0], sp1 = ws[OFF_SP + bs * 2 + 1];
    float offd = -(sp0 * ws[OFF_GFD + d * 2 + 0] + sp1 * ws[OFF_GFD + d * 2 + 1]);
    ws[OFF_OQ + (bs * 128 + d) * 2 + 0] = offd;
    ws[OFF_OQ + (bs * 128 + d) * 2 + 1] = qf * SCALE;
  }
}

__global__ __launch_bounds__(256) void kBaseQ(const float* __restrict__ Wq,
                                              const float* __restrict__ f_b2,
                                              const float* __restrict__ lnsg,
                                              const float* __restrict__ lnsb,
                                              float* __restrict__ ws) {
  __shared__ __align__(16) char smem[17408];
  int blk = blockIdx.x;
  if (blk >= 512) {       // initial q projection blocks
    doQ(blk - 512, Wq, f_b2, lnsg, lnsb, ws, *reinterpret_cast<QSm*>(smem));
    return;
  }
  char* ep = smem;
  const ushort_t* ab = (const ushort_t*)(ws + OFF_AB);
  int tid = threadIdx.x, w = tid >> 6, l = tid & 63;
  int lr = l & 15, lg = l >> 4;
  int mat = blk >> 8;
  int rb = blk & 255;
  int rowblk = rb * 128;
  int b = rb >> 5;
  int nb_in_b = (rb & 31) * 128;
  const ushort_t* Wg = (const ushort_t*)(ws + (mat ? OFF_WVB : OFF_WKB));

  short8 afrag[2][4];
#pragma unroll
  for (int rt = 0; rt < 2; ++rt)
#pragma unroll
    for (int ks = 0; ks < 4; ++ks) {
      size_t row = (size_t)rowblk + w * 32 + rt * 16 + lr;
      afrag[rt][ks] = *(const short8*)(ab + row * 128 + ks * 32 + lg * 8);
    }
  float gf0a[8], gf1a[8], cba[8];
#pragma unroll
  for (int ct = 0; ct < 8; ++ct) {
    int c = ct * 16 + lr;
    gf0a[ct] = ws[OFF_GFD + c * 2 + 0];
    gf1a[ct] = ws[OFF_GFD + c * 2 + 1];
    cba[ct]  = ws[OFF_CB + c];
  }
  f32x4 acc[2][8];
#pragma unroll
  for (int rt = 0; rt < 2; ++rt)
#pragma unroll
    for (int ct = 0; ct < 8; ++ct) acc[rt][ct] = (f32x4){0.f, 0.f, 0.f, 0.f};
#pragma unroll 2
  for (int ct = 0; ct < 8; ++ct) {
    short8 bfr[4];
#pragma unroll
    for (int ks = 0; ks < 4; ++ks)
      bfr[ks] = *(const short8*)(Wg + (ct * 16 + lr) * 128 + ks * 32 + lg * 8);
#pragma unroll
    for (int ks = 0; ks < 4; ++ks) {
      acc[0][ct] = __builtin_amdgcn_mfma_f32_16x16x32_bf16(afrag[0][ks], bfr[ks], acc[0][ct], 0, 0, 0);
      acc[1][ct] = __builtin_amdgcn_mfma_f32_16x16x32_bf16(afrag[1][ks], bfr[ks], acc[1][ct], 0, 0, 0);
    }
  }
  uint_t* outK = (uint_t*)(ws + OFF_BKT);
  ushort_t* outV = (ushort_t*)(ws + OFF_BV);
  for (int h = 0; h < 2; ++h) {
    __syncthreads();
    if ((w >> 1) == h) {
      int nl0 = (w & 1) * 32 + lg * 4;
#pragma unroll
      for (int rt = 0; rt < 2; ++rt)
#pragma unroll
        for (int ct = 0; ct < 8; ++ct) {
          int c = ct * 16 + lr;
          ushort_t pk[4];
#pragma unroll
          for (int r = 0; r < 4; ++r) {
            int n = nb_in_b + h * 64 + nl0 + rt * 16 + r;
            float gy = -1.f + (float)(n >> 6) * (2.f / 63.f);
            float gx = -1.f + (float)(n & 63) * (2.f / 63.f);
            float o = acc[rt][ct][r] + gy * gf0a[ct] + gx * gf1a[ct] + cba[ct];
            pk[r] = f2bf(o);
          }
          if (mat == 0) {
            int byte = (c * 128 + (nl0 + rt * 16) * 2) ^ ((c & 7) << 4);
            *(uint2*)(ep + byte) = make_uint2(
                (uint_t)pk[0] | ((uint_t)pk[1] << 16),
                (uint_t)pk[2] | ((uint_t)pk[3] << 16));
          } else {
            int rbw = nl0 + rt * 16;
#pragma unroll
            for (int r = 0; r < 4; ++r)
              *(ushort_t*)(ep + (rbw + r) * 272 + c * 2) = pk[r];
          }
        }
    }
    __syncthreads();
    if (mat == 0) {
      // packed store: dp-pair interleave -> BKT[b][dp][n] of uint(2 bf16)
      for (int idx = tid; idx < 1024; idx += 256) {
        int dp = idx >> 4, j = idx & 15;
        int c0 = 2 * dp, c1 = 2 * dp + 1;
        uint2 aA = *(const uint2*)(ep + ((c0 * 128 + j * 8) ^ ((c0 & 7) << 4)));
        uint2 bA = *(const uint2*)(ep + ((c1 * 128 + j * 8) ^ ((c1 & 7) << 4)));
        uint4 o;
        o.x = (aA.x & 0xffffu) | (bA.x << 16);
        o.y = (aA.x >> 16) | (bA.x & 0xffff0000u);
        o.z = (aA.y & 0xffffu) | (bA.y << 16);
        o.w = (aA.y >> 16) | (bA.y & 0xffff0000u);
        *(uint4*)(outK + ((size_t)(b * 64 + dp)) * 4096 + nb_in_b + h * 64 + j * 4) = o;
      }
    } else {
      for (int idx = tid; idx < 1024; idx += 256) {
        int nl = idx >> 4, j = idx & 15;
        uint4 v = *(const uint4*)(ep + nl * 272 + j * 16);
        *(uint4*)(outV + ((size_t)rowblk + h * 64 + nl) * 128 + j * 8) = v;
      }
    }
  }
}

// ---------------- fused attention: 4 waves, d-split / i-split ----------------
__global__ __launch_bounds__(256) void kAttn(float* __restrict__ ws) {
  __shared__ __align__(16) float OFFl[8][128];
  __shared__ __align__(16) float QFl[8][128];
  __shared__ float tp[64][37];
  __shared__ __align__(16) float al[64][12];
  __shared__ float Ush[4][8][132];
  int b = blockIdx.x >> 6, chunk = blockIdx.x & 63;
  int tid = threadIdx.x, w = tid >> 6, lane = tid & 63;
  int sb = b * 8;
  for (int f = tid; f < 1024; f += 256) {
    int s = f >> 7, d = f & 127;
    float2 oq = *(const float2*)&ws[OFF_OQ + ((sb + s) * 128 + d) * 2];
    OFFl[s][d] = oq.x;
    QFl[s][d] = oq.y;
  }
  float qbl[8];
#pragma unroll
  for (int s = 0; s < 8; ++s) qbl[s] = ws[OFF_QB + sb + s];
  __syncthreads();

  // phase 1: pixel-per-lane dots, d-pair packed K
  int n = chunk * 64 + lane;
  const uint_t* kpp = (const uint_t*)(ws + OFF_BKT) +
                      (size_t)b * 262144 + (size_t)(w * 16) * 4096 + n;
  float t[8];
#pragma unroll
  for (int s = 0; s < 8; ++s) t[s] = 0.f;
#pragma unroll 4
  for (int dp = 0; dp < 16; ++dp) {
    uint_t v = kpp[(size_t)dp * 4096];
    float k0 = bf2f(v & 0xffffu);
    float k1 = bf2f(v >> 16);
    int d0 = w * 32 + 2 * dp;
#pragma unroll
    for (int s = 0; s < 8; ++s) {
      float2 ofp = *(const float2*)&OFFl[s][d0];
      float2 qfp = *(const float2*)&QFl[s][d0];
      t[s] = fmaf(fmaxf(k0 + ofp.x, 0.f), qfp.x, t[s]);
      t[s] = fmaf(fmaxf(k1 + ofp.y, 0.f), qfp.y, t[s]);
    }
  }
#pragma unroll
  for (int s = 0; s < 8; ++s) tp[lane][s * 4 + w] = t[s];
  __syncthreads();
  float a[8], den = 0.f;
#pragma unroll
  for (int s = 0; s < 8; ++s)
    t[s] = tp[lane][s * 4 + 0] + tp[lane][s * 4 + 1] +
           tp[lane][s * 4 + 2] + tp[lane][s * 4 + 3] + qbl[s];
  float mx = t[0];
#pragma unroll
  for (int s = 1; s < 8; ++s) mx = fmaxf(mx, t[s]);
#pragma unroll
  for (int s = 0; s < 8; ++s) { a[s] = __expf(t[s] - mx); den += a[s]; }
  float inv = 1.0f / den;
#pragma unroll
  for (int s = 0; s < 8; ++s) a[s] = fmaf(a[s], inv, EPS_);
  if (w == 0) {
    float gy = -1.f + (float)(n >> 6) * (2.f / 63.f);
    float gx = -1.f + (float)(n & 63) * (2.f / 63.f);
#pragma unroll
    for (int s = 0; s < 8; ++s) al[lane][s] = a[s];
#pragma unroll
    for (int s = 0; s < 8; ++s) {
      float z = waveReduceSum(a[s]);
      float p0 = waveReduceSum(a[s] * gy);
      float p1 = waveReduceSum(a[s] * gx);
      if (lane == 0) {
        ws[OFF_ZP + (b * 64 + chunk) * 8 + s] = z;
        ws[OFF_PP + ((b * 64 + chunk) * 8 + s) * 2 + 0] = p0;
        ws[OFF_PP + ((b * 64 + chunk) * 8 + s) * 2 + 1] = p1;
      }
    }
  }
  __syncthreads();

  // phase 2: channel-pair-per-lane over this wave's 16 pixels
  int c0 = 2 * lane;
  float offv0[8], offv1[8];
#pragma unroll
  for (int s = 0; s < 8; ++s) {
    float2 of2 = *(const float2*)&OFFl[s][c0];
    offv0[s] = of2.x;
    offv1[s] = of2.y;
  }
  float Ua0[8], Ua1[8];
#pragma unroll
  for (int s = 0; s < 8; ++s) { Ua0[s] = 0.f; Ua1[s] = 0.f; }
  const ushort_t* vp = (const ushort_t*)(ws + OFF_BV) +
                       ((size_t)(b * 4096 + chunk * 64 + w * 16)) * 128 + c0;
#pragma unroll 4
  for (int i = 0; i < 16; ++i) {
    uint_t vraw = *(const uint_t*)(vp + (size_t)i * 128);
    float v0 = bf2f(vraw & 0xffffu);
    float v1 = bf2f(vraw >> 16);
    int ii = w * 16 + i;
    float4 a0 = *(const float4*)&al[ii][0];
    float4 a1 = *(const float4*)&al[ii][4];
    float asv[8] = {a0.x, a0.y, a0.z, a0.w, a1.x, a1.y, a1.z, a1.w};
#pragma unroll
    for (int s = 0; s < 8; ++s) {
      Ua0[s] = fmaf(asv[s], fmaxf(v0 + offv0[s], 0.f), Ua0[s]);
      Ua1[s] = fmaf(asv[s], fmaxf(v1 + offv1[s], 0.f), Ua1[s]);
    }
  }
#pragma unroll
  for (int s = 0; s < 8; ++s) {
    Ush[w][s][c0] = Ua0[s];
    Ush[w][s][c0 + 1] = Ua1[s];
  }
  __syncthreads();
  for (int f = tid; f < 1024; f += 256) {
    int s = f >> 7, c = f & 127;
    float v = Ush[0][s][c] + Ush[1][s][c] + Ush[2][s][c] + Ush[3][s][c];
    ws[OFF_UP + ((size_t)(b * 64 + chunk) * 8 + s) * 128 + c] = v;
  }
}

// ---------------- fused: finalize + GRU + post-MLP + next-iter q ----------------
__global__ __launch_bounds__(512) void kCQ(
    const float* __restrict__ Wq, const float* __restrict__ f_w2,
    const float* __restrict__ f_b2, const float* __restrict__ wih,
    const float* __restrict__ whh, const float* __restrict__ bih,
    const float* __restrict__ bhh, const float* __restrict__ mw1,
    const float* __restrict__ mb1, const float* __restrict__ mw2,
    const float* __restrict__ mb2, const float* __restrict__ lnpg,
    const float* __restrict__ lnpb, const float* __restrict__ lnsg,
    const float* __restrict__ lnsb, const float* __restrict__ S_r,
    const float* __restrict__ S_s, float* __restrict__ ws,
    float* __restrict__ out, int last) {
  int bs = blockIdx.x;
  int t = threadIdx.x;
  if (bs == 64) {         // only on last iter: S_r / S_s passthrough
    if (t < 256) out[8320 + t] = S_r[t];
    else if (t < 384) out[8576 + t - 256] = S_s[t - 256];
    return;
  }
  int b = bs >> 3, s = bs & 7;
  int w = t >> 6, lane = t & 63;
  int d = t >> 2, h = t & 3;
  __shared__ __align__(16) float ul[128], xl[128], sl[128], yl[128], hml[128];
  __shared__ float red[8], red2[8];
  const float* FW2T = ws + OFF_FW2T;
  float zv = ws[OFF_ZP + (b * 64 + lane) * 8 + s];
  float2 pv = *(const float2*)&ws[OFF_PP + ((size_t)(b * 64 + lane) * 8 + s) * 2];
  float Z = waveReduceSum(zv);
  float P0 = waveReduceSum(pv.x);
  float P1 = waveReduceSum(pv.y);
  float invZ = 1.f / Z, sp0 = P0 * invZ, sp1 = P1 * invZ;
  float u = 0.f;
  const float* up = ws + OFF_UP + ((size_t)(b * 64 + h * 16) * 8 + s) * 128 + d;
#pragma unroll
  for (int ch = 0; ch < 16; ++ch) u += up[(size_t)ch * 1024];
  u = quadSum(u);
  if (h == 0) { ul[d] = u * invZ; sl[d] = ws[OFF_SLOTS + bs * 128 + d]; }
  if (t == 0) {
    ws[OFF_SP + bs * 2 + 0] = sp0;
    ws[OFF_SP + bs * 2 + 1] = sp1;
    if (last) {
      out[8192 + bs * 2 + 0] = sp0;
      out[8192 + bs * 2 + 1] = sp1;
    }
  }
  __syncthreads();
  float xa = quadSum(quarterDot(f_w2 + (size_t)d * 128, ul, h));
  if (h == 0) xl[d] = xa + f_b2[d];
  __syncthreads();
  float ir = quarterDot(wih + (size_t)d * 128, xl, h);
  float iz = quarterDot(wih + (size_t)(128 + d) * 128, xl, h);
  float in_ = quarterDot(wih + (size_t)(256 + d) * 128, xl, h);
  float hr = quarterDot(whh + (size_t)d * 128, sl, h);
  float hz = quarterDot(whh + (size_t)(128 + d) * 128, sl, h);
  float hn = quarterDot(whh + (size_t)(256 + d) * 128, sl, h);
  ir = quadSum(ir); iz = quadSum(iz); in_ = quadSum(in_);
  hr = quadSum(hr); hz = quadSum(hz); hn = quadSum(hn);
  float hnew = 0.f;
  if (h == 0) {
    float rg = 1.f / (1.f + __expf(-(ir + bih[d] + hr + bhh[d])));
    float zg = 1.f / (1.f + __expf(-(iz + bih[128 + d] + hz + bhh[128 + d])));
    float ng = tanhf(in_ + bih[256 + d] + rg * (hn + bhh[256 + d]));
    hnew = (1.f - zg) * ng + zg * sl[d];
  }
  float m1 = waveReduceSum(h == 0 ? hnew : 0.f);
  float m2 = waveReduceSum(h == 0 ? hnew * hnew : 0.f);
  if (lane == 0) { red[w] = m1; red2[w] = m2; }
  __syncthreads();
  float mean = 0.f, var = 0.f;
#pragma unroll
  for (int i = 0; i < 8; ++i) { mean += red[i]; var += red2[i]; }
  mean *= (1.f / 128.f);
  var = var * (1.f / 128.f) - mean * mean;
  if (h == 0) yl[d] = (hnew - mean) * rsqrtf(var + LN_EPS_) * lnpg[d] + lnpb[d];
  __syncthreads();
  float hm = quadSum(quarterDot(mw1 + (size_t)d * 128, yl, h));
  if (h == 0) hml[d] = fmaxf(hm + mb1[d], 0.f);
  __syncthreads();
  float oa = quadSum(quarterDot(mw2 + (size_t)d * 128, hml, h));
  float o = 0.f;
  if (h == 0) {
    o = hnew + mb2[d] + oa;
    ws[OFF_SLOTS + bs * 128 + d] = o;
    if (last) out[bs * 128 + d] = o;
  }
  float n1 = waveReduceSum(h == 0 ? o : 0.f);
  float n2 = waveReduceSum(h == 0 ? o * o : 0.f);
  if (lane == 0) { red[w] = n1; red2[w] = n2; }
  __syncthreads();
  float mean2 = 0.f, var2 = 0.f;
#pragma unroll
  for (int i = 0; i < 8; ++i) { mean2 += red[i]; var2 += red2[i]; }
  mean2 *= (1.f / 128.f);
  var2 = var2 * (1.f / 128.f) - mean2 * mean2;
  if (h == 0) yl[d] = (o - mean2) * rsqrtf(var2 + LN_EPS_) * lnsg[d] + lnsb[d];
  __syncthreads();
  float q = quadSum(quarterDot(Wq + (size_t)d * 128, yl, h));
  if (h == 0) xl[d] = q;
  __syncthreads();
  float qv = waveReduceSum(h == 0 ? q * f_b2[d] : 0.f);
  if (lane == 0) red[w] = qv;
  float qf = quadSum(quarterDot(FW2T + (size_t)d * 128, xl, h));
  __syncthreads();
  if (t == 0) {
    float qb = 0.f;
#pragma unroll
    for (int i = 0; i < 8; ++i) qb += red[i];
    ws[OFF_QB + bs] = qb * SCALE;
  }
  if (h == 0) {
    float offd = -(sp0 * ws[OFF_GFD + d * 2 + 0] + sp1 * ws[OFF_GFD + d * 2 + 1]);
    ws[OFF_OQ + (bs * 128 + d) * 2 + 0] = offd;
    ws[OFF_OQ + (bs * 128 + d) * 2 + 1] = qf * SCALE;
  }
}

extern "C" void kernel_launch(void* const* d_in, const int* in_sizes, int n_in,
                              void* d_out, int out_size, void* d_ws, size_t ws_size,
                              hipStream_t stream) {
  const float* inputs     = (const float*)d_in[0];
  const float* slots_init = (const float*)d_in[1];
  const float* S_p0       = (const float*)d_in[2];
  const float* S_s        = (const float*)d_in[3];
  const float* S_r        = (const float*)d_in[4];
  const float* Wq   = (const float*)d_in[5];
  const float* Wk   = (const float*)d_in[6];
  const float* Wv   = (const float*)d_in[7];
  const float* g_w  = (const float*)d_in[8];
  const float* g_b  = (const float*)d_in[9];
  const float* f_w1 = (const float*)d_in[10];
  const float* f_b1 = (const float*)d_in[11];
  const float* f_w2 = (const float*)d_in[12];
  const float* f_b2 = (const float*)d_in[13];
  const float* gwih = (const float*)d_in[14];
  const float* gwhh = (const float*)d_in[15];
  const float* gbih = (const float*)d_in[16];
  const float* gbhh = (const float*)d_in[17];
  const float* mw1  = (const float*)d_in[18];
  const float* mb1  = (const float*)d_in[19];
  const float* mw2  = (const float*)d_in[20];
  const float* mb2  = (const float*)d_in[21];
  const float* lnsg = (const float*)d_in[22];
  const float* lnsb = (const float*)d_in[23];
  const float* lnpg = (const float*)d_in[24];
  const float* lnpb = (const float*)d_in[25];
  float* ws  = (float*)d_ws;
  float* out = (float*)d_out;

  kFold<<<392, 256, 0, stream>>>(f_w1, Wk, Wv, g_w, g_b, f_b1, f_w2,
                                 slots_init, S_p0, inputs, ws);
  kBaseQ<<<576, 256, 0, stream>>>(Wq, f_b2, lnsg, lnsb, ws);
  for (int it = 0; it < 3; ++it) {
    int last = (it == 2);
    kAttn<<<512, 256, 0, stream>>>(ws);
    kCQ<<<64 + last, 512, 0, stream>>>(Wq, f_w2, f_b2, gwih, gwhh, gbih, gbhh,
                                       mw1, mb1, mw2, mb2, lnpg, lnpb,
                                       lnsg, lnsb, S_r, S_s, ws, out, last);
  }
}

// Round 11
// 165.568 us; speedup vs baseline: 4.4066x; 1.0714x over previous
//
#include <hip/hip_runtime.h>
#include <cstdint>
#include <cstddef>

#define SCALE  0.08838834764831845f   // 128^-0.5
#define EPS_   1e-8f
#define LN_EPS_ 1e-5f

typedef unsigned short ushort_t;
typedef unsigned int uint_t;
typedef __attribute__((ext_vector_type(8))) short short8;
typedef __attribute__((ext_vector_type(4))) float f32x4;

// ---------------- workspace layout (float offsets), 23.3 MB ----------------
constexpr int OFF_GFD   = 0;        // 256   (f_w1@g_w)/DELTA  [h][2]
constexpr int OFF_CB    = 256;      // 128   f_w1@g_b + f_b1
constexpr int OFF_QB    = 384;      // 64
constexpr int OFF_SP    = 448;      // 128
constexpr int OFF_OQ    = 576;      // 16384 interleaved (off, qf*scale)
constexpr int OFF_SLOTS = 16960;    // 8192
constexpr int OFF_ZP    = 25152;    // 4096   [b][64][8]
constexpr int OFF_PP    = 29248;    // 8192   [b][64][8][2]
constexpr int OFF_UP    = 37440;    // 524288 [b][64][8][128]
constexpr int OFF_WKB   = 561728;   // bf16 [128][128] = 8192 float-slots
constexpr int OFF_WVB   = 569920;   // 8192
constexpr int OFF_FW2T  = 578112;   // f32 f_w2^T 16384
constexpr int OFF_BKT   = 594496;   // uint [b][64 dp][4096 n] = 2097152 float-slots
constexpr int OFF_BV    = 2691648;  // bf16 [b][4096][128] = 2097152 float-slots
constexpr int OFF_AB    = 4788800;  // bf16 inputs [32768][128] = 1048576 float-slots
// end: 5837376 floats

__device__ __forceinline__ float waveReduceSum(float v) {
#pragma unroll
  for (int m = 1; m < 64; m <<= 1) v += __shfl_xor(v, m, 64);
  return v;
}
__device__ __forceinline__ float bf2f(uint_t u) { return __uint_as_float(u << 16); }
__device__ __forceinline__ ushort_t f2bf(float f) {
  uint_t u = __float_as_uint(f);
  return (ushort_t)((u + 0x7fffu + ((u >> 16) & 1u)) >> 16);
}

// half-row dot (e-range [h*64, h*64+64)), 16 independent float4 loads
__device__ __forceinline__ float halfDot(const float* __restrict__ Wrow,
                                         const float* xv, int h) {
  const float4* wr = (const float4*)Wrow + h * 16;
  const float4* xr = (const float4*)xv + h * 16;
  float4 a = {0.f, 0.f, 0.f, 0.f};
#pragma unroll
  for (int i = 0; i < 16; ++i) {
    float4 wv = wr[i], xq = xr[i];
    a.x = fmaf(wv.x, xq.x, a.x);
    a.y = fmaf(wv.y, xq.y, a.y);
    a.z = fmaf(wv.z, xq.z, a.z);
    a.w = fmaf(wv.w, xq.w, a.w);
  }
  return (a.x + a.y) + (a.z + a.w);
}

// quarter-row dot (e-range [h*32, h*32+32)), 8 independent float4 loads
__device__ __forceinline__ float quarterDot(const float* __restrict__ Wrow,
                                            const float* xv, int h) {
  const float4* wr = (const float4*)Wrow + h * 8;
  const float4* xr = (const float4*)xv + h * 8;
  float4 a = {0.f, 0.f, 0.f, 0.f};
#pragma unroll
  for (int i = 0; i < 8; ++i) {
    float4 wv = wr[i], xq = xr[i];
    a.x = fmaf(wv.x, xq.x, a.x);
    a.y = fmaf(wv.y, xq.y, a.y);
    a.z = fmaf(wv.z, xq.z, a.z);
    a.w = fmaf(wv.w, xq.w, a.w);
  }
  return (a.x + a.y) + (a.z + a.w);
}
__device__ __forceinline__ float quadSum(float v) {
  v += __shfl_xor(v, 1, 64);
  v += __shfl_xor(v, 2, 64);
  return v;
}

// ---------------- fold weights + init copies + input cast ----------------
__global__ __launch_bounds__(256) void kFold(
    const float* __restrict__ f_w1, const float* __restrict__ Wk,
    const float* __restrict__ Wv, const float* __restrict__ g_w,
    const float* __restrict__ g_b, const float* __restrict__ f_b1,
    const float* __restrict__ f_w2, const float* __restrict__ slots_init,
    const float* __restrict__ S_p0, const float* __restrict__ inputs,
    float* __restrict__ ws) {
  int blk = blockIdx.x, tid = threadIdx.x;
  if (blk < 128) {
    int isV = blk >> 6;
    int idx = (blk & 63) * 256 + tid;           // 0..16383  (h*128+e)
    int h = idx >> 7, e = idx & 127;
    const float* Wm = isV ? Wv : Wk;
    float a = 0.f;
#pragma unroll 4
    for (int d = 0; d < 128; ++d) a = fmaf(f_w1[h * 128 + d], Wm[d * 128 + e], a);
    ((ushort_t*)(ws + (isV ? OFF_WVB : OFF_WKB)))[idx] = f2bf(a);
  } else if (blk == 128) {
    int h = tid >> 1, c = tid & 1;
    float a = 0.f;
    for (int d = 0; d < 128; ++d) a = fmaf(f_w1[h * 128 + d], g_w[d * 2 + c], a);
    ws[OFF_GFD + tid] = a * 0.2f;               // /DELTA (DELTA=5)
  } else if (blk == 129) {
    if (tid < 128) {
      float a = f_b1[tid];
      for (int d = 0; d < 128; ++d) a = fmaf(f_w1[tid * 128 + d], g_b[d], a);
      ws[OFF_CB + tid] = a;
    }
  } else if (blk == 130) {
    for (int i = tid; i < 16384; i += 256)
      ws[OFF_FW2T + (i & 127) * 128 + (i >> 7)] = f_w2[i];
  } else if (blk < 135) {
    int base = (blk - 131) * 2048 + tid * 8;    // slots copy, 8 floats/thread
    float4 a = *(const float4*)&slots_init[base];
    float4 b = *(const float4*)&slots_init[base + 4];
    *(float4*)&ws[OFF_SLOTS + base] = a;
    *(float4*)&ws[OFF_SLOTS + base + 4] = b;
  } else if (blk == 135) {
    if (tid < 128) ws[OFF_SP + tid] = S_p0[tid];
  } else {
    // input cast: blocks 136..391, 8 floats per thread
    int idx = (blk - 136) * 256 + tid;          // 0..65535
    const float4* src = (const float4*)(inputs + (size_t)idx * 8);
    float4 a = src[0], b = src[1];
    uint_t p0 = (uint_t)f2bf(a.x) | ((uint_t)f2bf(a.y) << 16);
    uint_t p1 = (uint_t)f2bf(a.z) | ((uint_t)f2bf(a.w) << 16);
    uint_t p2 = (uint_t)f2bf(b.x) | ((uint_t)f2bf(b.y) << 16);
    uint_t p3 = (uint_t)f2bf(b.z) | ((uint_t)f2bf(b.w) << 16);
    ((uint4*)((ushort_t*)(ws + OFF_AB)))[idx] = make_uint4(p0, p1, p2, p3);
  }
}

// ---------------- MFMA base GEMMs (64-row blocks) + initial q ----------------
struct QSm { float yl[128]; float ql[128]; float red[4]; float red2[4]; };

__device__ void doQ(int bs, const float* __restrict__ Wq,
                    const float* __restrict__ f_b2,
                    const float* __restrict__ lnsg,
                    const float* __restrict__ lnsb,
                    float* __restrict__ ws, QSm& S) {
  int t = threadIdx.x, w = t >> 6, lane = t & 63;
  int d = w * 32 + (lane >> 1), h = lane & 1;
  const float* FW2T = ws + OFF_FW2T;
  float x = ws[OFF_SLOTS + bs * 128 + d];
  float m1 = waveReduceSum(h == 0 ? x : 0.f);
  float m2 = waveReduceSum(h == 0 ? x * x : 0.f);
  if (lane == 0) { S.red[w] = m1; S.red2[w] = m2; }
  __syncthreads();
  float mean = (S.red[0] + S.red[1] + S.red[2] + S.red[3]) * (1.f / 128.f);
  float var = (S.red2[0] + S.red2[1] + S.red2[2] + S.red2[3]) * (1.f / 128.f) - mean * mean;
  if (h == 0) S.yl[d] = (x - mean) * rsqrtf(var + LN_EPS_) * lnsg[d] + lnsb[d];
  __syncthreads();
  float q = halfDot(Wq + (size_t)d * 128, S.yl, h);
  q += __shfl_xor(q, 1, 64);
  if (h == 0) S.ql[d] = q;
  __syncthreads();
  float qv = waveReduceSum(h == 0 ? q * f_b2[d] : 0.f);
  if (lane == 0) S.red[w] = qv;
  float qf = halfDot(FW2T + (size_t)d * 128, S.ql, h);
  qf += __shfl_xor(qf, 1, 64);
  __syncthreads();
  if (t == 0) ws[OFF_QB + bs] = (S.red[0] + S.red[1] + S.red[2] + S.red[3]) * SCALE;
  if (h == 0) {
    float sp0 = ws[OFF_SP + bs * 2 + 0], sp1 = ws[OFF_SP + bs * 2 + 1];
    float offd = -(sp0 * ws[OFF_GFD + d * 2 + 0] + sp1 * ws[OFF_GFD + d * 2 + 1]);
    ws[OFF_OQ + (bs * 128 + d) * 2 + 0] = offd;
    ws[OFF_OQ + (bs * 128 + d) * 2 + 1] = qf * SCALE;
  }
}

// grid: 1024 GEMM blocks (mat = blk>>9, rb = blk&511, 64 rows each) + 64 doQ
__global__ __launch_bounds__(256) void kBaseQ(const float* __restrict__ Wq,
                                              const float* __restrict__ f_b2,
                                              const float* __restrict__ lnsg,
                                              const float* __restrict__ lnsb,
                                              float* __restrict__ ws) {
  __shared__ __align__(16) char smem[17408];
  int blk = blockIdx.x;
  if (blk >= 1024) {      // initial q projection blocks
    doQ(blk - 1024, Wq, f_b2, lnsg, lnsb, ws, *reinterpret_cast<QSm*>(smem));
    return;
  }
  char* ep = smem;
  const ushort_t* ab = (const ushort_t*)(ws + OFF_AB);
  int tid = threadIdx.x, w = tid >> 6, l = tid & 63;
  int lr = l & 15, lg = l >> 4;
  int mat = blk >> 9;
  int rb = blk & 511;                 // 0..511 (64-row block index)
  int b = rb >> 6;
  int n0 = (rb & 63) * 64;            // pixel base within batch
  const ushort_t* Wg = (const ushort_t*)(ws + (mat ? OFF_WVB : OFF_WKB));

  // A fragments: wave w owns rows n0 + w*16 + lr (global row = b*4096 + ...)
  short8 afrag[4];
#pragma unroll
  for (int ks = 0; ks < 4; ++ks) {
    size_t row = (size_t)b * 4096 + n0 + w * 16 + lr;
    afrag[ks] = *(const short8*)(ab + row * 128 + ks * 32 + lg * 8);
  }
  float gf0a[8], gf1a[8], cba[8];
#pragma unroll
  for (int ct = 0; ct < 8; ++ct) {
    int c = ct * 16 + lr;
    gf0a[ct] = ws[OFF_GFD + c * 2 + 0];
    gf1a[ct] = ws[OFF_GFD + c * 2 + 1];
    cba[ct]  = ws[OFF_CB + c];
  }
  f32x4 acc[8];
#pragma unroll
  for (int ct = 0; ct < 8; ++ct) acc[ct] = (f32x4){0.f, 0.f, 0.f, 0.f};
#pragma unroll 2
  for (int ct = 0; ct < 8; ++ct) {
    short8 bfr[4];
#pragma unroll
    for (int ks = 0; ks < 4; ++ks)
      bfr[ks] = *(const short8*)(Wg + (ct * 16 + lr) * 128 + ks * 32 + lg * 8);
#pragma unroll
    for (int ks = 0; ks < 4; ++ks)
      acc[ct] = __builtin_amdgcn_mfma_f32_16x16x32_bf16(afrag[ks], bfr[ks], acc[ct], 0, 0, 0);
  }
  // epilogue: every wave writes its own 16-row C fragment into ep
#pragma unroll
  for (int ct = 0; ct < 8; ++ct) {
    int c = ct * 16 + lr;
    ushort_t pk[4];
#pragma unroll
    for (int r = 0; r < 4; ++r) {
      int nl = w * 16 + lg * 4 + r;          // 0..63 within block
      int n = n0 + nl;                        // pixel index in batch
      float gy = -1.f + (float)(n >> 6) * (2.f / 63.f);
      float gx = -1.f + (float)(n & 63) * (2.f / 63.f);
      float o = acc[ct][r] + gy * gf0a[ct] + gx * gf1a[ct] + cba[ct];
      pk[r] = f2bf(o);
    }
    if (mat == 0) {       // epK: [c:128][n:64] bf16 rows of 128B, swizzled
      int nl0 = w * 16 + lg * 4;
      int byte = (c * 128 + nl0 * 2) ^ ((c & 7) << 4);
      *(uint2*)(ep + byte) = make_uint2(
          (uint_t)pk[0] | ((uint_t)pk[1] << 16),
          (uint_t)pk[2] | ((uint_t)pk[3] << 16));
    } else {              // epV: [n:64][272B] bf16 rows
      int nl0 = w * 16 + lg * 4;
#pragma unroll
      for (int r = 0; r < 4; ++r)
        *(ushort_t*)(ep + (nl0 + r) * 272 + c * 2) = pk[r];
    }
  }
  __syncthreads();
  if (mat == 0) {
    uint_t* outK = (uint_t*)(ws + OFF_BKT);
    // packed store: dp-pair interleave -> BKT[b][dp][n] of uint(2 bf16)
    for (int idx = tid; idx < 1024; idx += 256) {
      int dp = idx >> 4, j = idx & 15;        // dp 0..63, j covers 64 n
      int c0 = 2 * dp, c1 = 2 * dp + 1;
      uint2 aA = *(const uint2*)(ep + ((c0 * 128 + j * 8) ^ ((c0 & 7) << 4)));
      uint2 bA = *(const uint2*)(ep + ((c1 * 128 + j * 8) ^ ((c1 & 7) << 4)));
      uint4 o;
      o.x = (aA.x & 0xffffu) | (bA.x << 16);
      o.y = (aA.x >> 16) | (bA.x & 0xffff0000u);
      o.z = (aA.y & 0xffffu) | (bA.y << 16);
      o.w = (aA.y >> 16) | (bA.y & 0xffff0000u);
      *(uint4*)(outK + ((size_t)(b * 64 + dp)) * 4096 + n0 + j * 4) = o;
    }
  } else {
    ushort_t* outV = (ushort_t*)(ws + OFF_BV);
    for (int idx = tid; idx < 1024; idx += 256) {
      int nl = idx >> 4, j = idx & 15;
      uint4 v = *(const uint4*)(ep + nl * 272 + j * 16);
      *(uint4*)(outV + ((size_t)rb * 64 + nl) * 128 + j * 8) = v;
    }
  }
}

// ---------------- fused attention: 4 waves, d-split / i-split ----------------
__global__ __launch_bounds__(256) void kAttn(float* __restrict__ ws) {
  __shared__ __align__(16) float OFFl[8][128];
  __shared__ __align__(16) float QFl[8][128];
  __shared__ float tp[64][37];
  __shared__ __align__(16) float al[64][12];
  __shared__ float Ush[4][8][132];
  int b = blockIdx.x >> 6, chunk = blockIdx.x & 63;
  int tid = threadIdx.x, w = tid >> 6, lane = tid & 63;
  int sb = b * 8;
  for (int f = tid; f < 1024; f += 256) {
    int s = f >> 7, d = f & 127;
    float2 oq = *(const float2*)&ws[OFF_OQ + ((sb + s) * 128 + d) * 2];
    OFFl[s][d] = oq.x;
    QFl[s][d] = oq.y;
  }
  float qbl[8];
#pragma unroll
  for (int s = 0; s < 8; ++s) qbl[s] = ws[OFF_QB + sb + s];
  __syncthreads();

  // phase 1: pixel-per-lane dots, d-pair packed K
  int n = chunk * 64 + lane;
  const uint_t* kpp = (const uint_t*)(ws + OFF_BKT) +
                      (size_t)b * 262144 + (size_t)(w * 16) * 4096 + n;
  float t[8];
#pragma unroll
  for (int s = 0; s < 8; ++s) t[s] = 0.f;
#pragma unroll 4
  for (int dp = 0; dp < 16; ++dp) {
    uint_t v = kpp[(size_t)dp * 4096];
    float k0 = bf2f(v & 0xffffu);
    float k1 = bf2f(v >> 16);
    int d0 = w * 32 + 2 * dp;
#pragma unroll
    for (int s = 0; s < 8; ++s) {
      float2 ofp = *(const float2*)&OFFl[s][d0];
      float2 qfp = *(const float2*)&QFl[s][d0];
      t[s] = fmaf(fmaxf(k0 + ofp.x, 0.f), qfp.x, t[s]);
      t[s] = fmaf(fmaxf(k1 + ofp.y, 0.f), qfp.y, t[s]);
    }
  }
#pragma unroll
  for (int s = 0; s < 8; ++s) tp[lane][s * 4 + w] = t[s];
  __syncthreads();
  float a[8], den = 0.f;
#pragma unroll
  for (int s = 0; s < 8; ++s)
    t[s] = tp[lane][s * 4 + 0] + tp[lane][s * 4 + 1] +
           tp[lane][s * 4 + 2] + tp[lane][s * 4 + 3] + qbl[s];
  float mx = t[0];
#pragma unroll
  for (int s = 1; s < 8; ++s) mx = fmaxf(mx, t[s]);
#pragma unroll
  for (int s = 0; s < 8; ++s) { a[s] = __expf(t[s] - mx); den += a[s]; }
  float inv = 1.0f / den;
#pragma unroll
  for (int s = 0; s < 8; ++s) a[s] = fmaf(a[s], inv, EPS_);
  if (w == 0) {
    float gy = -1.f + (float)(n >> 6) * (2.f / 63.f);
    float gx = -1.f + (float)(n & 63) * (2.f / 63.f);
#pragma unroll
    for (int s = 0; s < 8; ++s) al[lane][s] = a[s];
#pragma unroll
    for (int s = 0; s < 8; ++s) {
      float z = waveReduceSum(a[s]);
      float p0 = waveReduceSum(a[s] * gy);
      float p1 = waveReduceSum(a[s] * gx);
      if (lane == 0) {
        ws[OFF_ZP + (b * 64 + chunk) * 8 + s] = z;
        ws[OFF_PP + ((b * 64 + chunk) * 8 + s) * 2 + 0] = p0;
        ws[OFF_PP + ((b * 64 + chunk) * 8 + s) * 2 + 1] = p1;
      }
    }
  }
  __syncthreads();

  // phase 2: channel-pair-per-lane over this wave's 16 pixels
  int c0 = 2 * lane;
  float offv0[8], offv1[8];
#pragma unroll
  for (int s = 0; s < 8; ++s) {
    float2 of2 = *(const float2*)&OFFl[s][c0];
    offv0[s] = of2.x;
    offv1[s] = of2.y;
  }
  float Ua0[8], Ua1[8];
#pragma unroll
  for (int s = 0; s < 8; ++s) { Ua0[s] = 0.f; Ua1[s] = 0.f; }
  const ushort_t* vp = (const ushort_t*)(ws + OFF_BV) +
                       ((size_t)(b * 4096 + chunk * 64 + w * 16)) * 128 + c0;
#pragma unroll 4
  for (int i = 0; i < 16; ++i) {
    uint_t vraw = *(const uint_t*)(vp + (size_t)i * 128);
    float v0 = bf2f(vraw & 0xffffu);
    float v1 = bf2f(vraw >> 16);
    int ii = w * 16 + i;
    float4 a0 = *(const float4*)&al[ii][0];
    float4 a1 = *(const float4*)&al[ii][4];
    float asv[8] = {a0.x, a0.y, a0.z, a0.w, a1.x, a1.y, a1.z, a1.w};
#pragma unroll
    for (int s = 0; s < 8; ++s) {
      Ua0[s] = fmaf(asv[s], fmaxf(v0 + offv0[s], 0.f), Ua0[s]);
      Ua1[s] = fmaf(asv[s], fmaxf(v1 + offv1[s], 0.f), Ua1[s]);
    }
  }
#pragma unroll
  for (int s = 0; s < 8; ++s) {
    Ush[w][s][c0] = Ua0[s];
    Ush[w][s][c0 + 1] = Ua1[s];
  }
  __syncthreads();
  for (int f = tid; f < 1024; f += 256) {
    int s = f >> 7, c = f & 127;
    float v = Ush[0][s][c] + Ush[1][s][c] + Ush[2][s][c] + Ush[3][s][c];
    ws[OFF_UP + ((size_t)(b * 64 + chunk) * 8 + s) * 128 + c] = v;
  }
}

// ---------------- fused: finalize + GRU + post-MLP + next-iter q ----------------
__global__ __launch_bounds__(512) void kCQ(
    const float* __restrict__ Wq, const float* __restrict__ f_w2,
    const float* __restrict__ f_b2, const float* __restrict__ wih,
    const float* __restrict__ whh, const float* __restrict__ bih,
    const float* __restrict__ bhh, const float* __restrict__ mw1,
    const float* __restrict__ mb1, const float* __restrict__ mw2,
    const float* __restrict__ mb2, const float* __restrict__ lnpg,
    const float* __restrict__ lnpb, const float* __restrict__ lnsg,
    const float* __restrict__ lnsb, const float* __restrict__ S_r,
    const float* __restrict__ S_s, float* __restrict__ ws,
    float* __restrict__ out, int last) {
  int bs = blockIdx.x;
  int t = threadIdx.x;
  if (bs == 64) {         // only on last iter: S_r / S_s passthrough
    if (t < 256) out[8320 + t] = S_r[t];
    else if (t < 384) out[8576 + t - 256] = S_s[t - 256];
    return;
  }
  int b = bs >> 3, s = bs & 7;
  int w = t >> 6, lane = t & 63;
  int d = t >> 2, h = t & 3;
  __shared__ __align__(16) float ul[128], xl[128], sl[128], yl[128], hml[128];
  __shared__ float red[8], red2[8];
  const float* FW2T = ws + OFF_FW2T;
  float zv = ws[OFF_ZP + (b * 64 + lane) * 8 + s];
  float2 pv = *(const float2*)&ws[OFF_PP + ((size_t)(b * 64 + lane) * 8 + s) * 2];
  float Z = waveReduceSum(zv);
  float P0 = waveReduceSum(pv.x);
  float P1 = waveReduceSum(pv.y);
  float invZ = 1.f / Z, sp0 = P0 * invZ, sp1 = P1 * invZ;
  float u = 0.f;
  const float* up = ws + OFF_UP + ((size_t)(b * 64 + h * 16) * 8 + s) * 128 + d;
#pragma unroll
  for (int ch = 0; ch < 16; ++ch) u += up[(size_t)ch * 1024];
  u = quadSum(u);
  if (h == 0) { ul[d] = u * invZ; sl[d] = ws[OFF_SLOTS + bs * 128 + d]; }
  if (t == 0) {
    ws[OFF_SP + bs * 2 + 0] = sp0;
    ws[OFF_SP + bs * 2 + 1] = sp1;
    if (last) {
      out[8192 + bs * 2 + 0] = sp0;
      out[8192 + bs * 2 + 1] = sp1;
    }
  }
  __syncthreads();
  float xa = quadSum(quarterDot(f_w2 + (size_t)d * 128, ul, h));
  if (h == 0) xl[d] = xa + f_b2[d];
  __syncthreads();
  float ir = quarterDot(wih + (size_t)d * 128, xl, h);
  float iz = quarterDot(wih + (size_t)(128 + d) * 128, xl, h);
  float in_ = quarterDot(wih + (size_t)(256 + d) * 128, xl, h);
  float hr = quarterDot(whh + (size_t)d * 128, sl, h);
  float hz = quarterDot(whh + (size_t)(128 + d) * 128, sl, h);
  float hn = quarterDot(whh + (size_t)(256 + d) * 128, sl, h);
  ir = quadSum(ir); iz = quadSum(iz); in_ = quadSum(in_);
  hr = quadSum(hr); hz = quadSum(hz); hn = quadSum(hn);
  float hnew = 0.f;
  if (h == 0) {
    float rg = 1.f / (1.f + __expf(-(ir + bih[d] + hr + bhh[d])));
    float zg = 1.f / (1.f + __expf(-(iz + bih[128 + d] + hz + bhh[128 + d])));
    float ng = tanhf(in_ + bih[256 + d] + rg * (hn + bhh[256 + d]));
    hnew = (1.f - zg) * ng + zg * sl[d];
  }
  float m1 = waveReduceSum(h == 0 ? hnew : 0.f);
  float m2 = waveReduceSum(h == 0 ? hnew * hnew : 0.f);
  if (lane == 0) { red[w] = m1; red2[w] = m2; }
  __syncthreads();
  float mean = 0.f, var = 0.f;
#pragma unroll
  for (int i = 0; i < 8; ++i) { mean += red[i]; var += red2[i]; }
  mean *= (1.f / 128.f);
  var = var * (1.f / 128.f) - mean * mean;
  if (h == 0) yl[d] = (hnew - mean) * rsqrtf(var + LN_EPS_) * lnpg[d] + lnpb[d];
  __syncthreads();
  float hm = quadSum(quarterDot(mw1 + (size_t)d * 128, yl, h));
  if (h == 0) hml[d] = fmaxf(hm + mb1[d], 0.f);
  __syncthreads();
  float oa = quadSum(quarterDot(mw2 + (size_t)d * 128, hml, h));
  float o = 0.f;
  if (h == 0) {
    o = hnew + mb2[d] + oa;
    ws[OFF_SLOTS + bs * 128 + d] = o;
    if (last) out[bs * 128 + d] = o;
  }
  float n1 = waveReduceSum(h == 0 ? o : 0.f);
  float n2 = waveReduceSum(h == 0 ? o * o : 0.f);
  if (lane == 0) { red[w] = n1; red2[w] = n2; }
  __syncthreads();
  float mean2 = 0.f, var2 = 0.f;
#pragma unroll
  for (int i = 0; i < 8; ++i) { mean2 += red[i]; var2 += red2[i]; }
  mean2 *= (1.f / 128.f);
  var2 = var2 * (1.f / 128.f) - mean2 * mean2;
  if (h == 0) yl[d] = (o - mean2) * rsqrtf(var2 + LN_EPS_) * lnsg[d] + lnsb[d];
  __syncthreads();
  float q = quadSum(quarterDot(Wq + (size_t)d * 128, yl, h));
  if (h == 0) xl[d] = q;
  __syncthreads();
  float qv = waveReduceSum(h == 0 ? q * f_b2[d] : 0.f);
  if (lane == 0) red[w] = qv;
  float qf = quadSum(quarterDot(FW2T + (size_t)d * 128, xl, h));
  __syncthreads();
  if (t == 0) {
    float qb = 0.f;
#pragma unroll
    for (int i = 0; i < 8; ++i) qb += red[i];
    ws[OFF_QB + bs] = qb * SCALE;
  }
  if (h == 0) {
    float offd = -(sp0 * ws[OFF_GFD + d * 2 + 0] + sp1 * ws[OFF_GFD + d * 2 + 1]);
    ws[OFF_OQ + (bs * 128 + d) * 2 + 0] = offd;
    ws[OFF_OQ + (bs * 128 + d) * 2 + 1] = qf * SCALE;
  }
}

extern "C" void kernel_launch(void* const* d_in, const int* in_sizes, int n_in,
                              void* d_out, int out_size, void* d_ws, size_t ws_size,
                              hipStream_t stream) {
  const float* inputs     = (const float*)d_in[0];
  const float* slots_init = (const float*)d_in[1];
  const float* S_p0       = (const float*)d_in[2];
  const float* S_s        = (const float*)d_in[3];
  const float* S_r        = (const float*)d_in[4];
  const float* Wq   = (const float*)d_in[5];
  const float* Wk   = (const float*)d_in[6];
  const float* Wv   = (const float*)d_in[7];
  const float* g_w  = (const float*)d_in[8];
  const float* g_b  = (const float*)d_in[9];
  const float* f_w1 = (const float*)d_in[10];
  const float* f_b1 = (const float*)d_in[11];
  const float* f_w2 = (const float*)d_in[12];
  const float* f_b2 = (const float*)d_in[13];
  const float* gwih = (const float*)d_in[14];
  const float* gwhh = (const float*)d_in[15];
  const float* gbih = (const float*)d_in[16];
  const float* gbhh = (const float*)d_in[17];
  const float* mw1  = (const float*)d_in[18];
  const float* mb1  = (const float*)d_in[19];
  const float* mw2  = (const float*)d_in[20];
  const float* mb2  = (const float*)d_in[21];
  const float* lnsg = (const float*)d_in[22];
  const float* lnsb = (const float*)d_in[23];
  const float* lnpg = (const float*)d_in[24];
  const float* lnpb = (const float*)d_in[25];
  float* ws  = (float*)d_ws;
  float* out = (float*)d_out;

  kFold<<<392, 256, 0, stream>>>(f_w1, Wk, Wv, g_w, g_b, f_b1, f_w2,
                                 slots_init, S_p0, inputs, ws);
  kBaseQ<<<1088, 256, 0, stream>>>(Wq, f_b2, lnsg, lnsb, ws);
  for (int it = 0; it < 3; ++it) {
    int last = (it == 2);
    kAttn<<<512, 256, 0, stream>>>(ws);
    kCQ<<<64 + last, 512, 0, stream>>>(Wq, f_w2, f_b2, gwih, gwhh, gbih, gbhh,
                                       mw1, mb1, mw2, mb2, lnpg, lnpb,
                                       lnsg, lnsb, S_r, S_s, ws, out, last);
  }
}